// Round 3
// baseline (715.086 us; speedup 1.0000x reference)
//
#include <hip/hip_runtime.h>
#include <hip/hip_bf16.h>

#define HID 128
#define NRAW 127
#define BSH 8          // 256 nodes per bucket
#define BNODES 256
#define APAD 68        // LDS row pitch in u32 (16B-aligned, breaks pow2 stride)

typedef __attribute__((ext_vector_type(8))) short short8;
typedef __attribute__((ext_vector_type(4))) float floatx4;

__device__ inline unsigned pack_bf2(float x, float y) {
    unsigned bx = __float_as_uint(x);
    unsigned by = __float_as_uint(y);
    bx += 0x7fffu + ((bx >> 16) & 1u);   // RNE
    by += 0x7fffu + ((by >> 16) & 1u);
    return (bx >> 16) | (by & 0xffff0000u);
}
__device__ inline float bf_lo(unsigned u) { return __uint_as_float(u << 16); }
__device__ inline float bf_hi(unsigned u) { return __uint_as_float(u & 0xffff0000u); }

// ---------------- CSR build: bucketed 2-phase counting sort ----------------

__global__ __launch_bounds__(256) void bucket_count_kernel(const int* __restrict__ dst,
                                                           int* __restrict__ gbucket,
                                                           int E, int NB) {
    __shared__ int hist[512];
    int t = threadIdx.x;
    for (int b = t; b < NB; b += 256) hist[b] = 0;
    __syncthreads();
    int base = blockIdx.x * 4096;
    #pragma unroll
    for (int j = 0; j < 16; ++j) {
        int e = base + j * 256 + t;
        if (e < E) atomicAdd(&hist[dst[e] >> BSH], 1);
    }
    __syncthreads();
    for (int b = t; b < NB; b += 256) {
        int v = hist[b];
        if (v) atomicAdd(&gbucket[b], v);
    }
}

__global__ void bucket_scan_kernel(const int* __restrict__ gbucket, int* __restrict__ bstart,
                                   int* __restrict__ gcur, int NB, int E) {
    __shared__ int sm[512];
    int t = threadIdx.x;
    int v = (t < NB) ? gbucket[t] : 0;
    sm[t] = v;
    __syncthreads();
    for (int off = 1; off < 512; off <<= 1) {
        int add = (t >= off) ? sm[t - off] : 0;
        __syncthreads();
        sm[t] += add;
        __syncthreads();
    }
    if (t < NB) {
        int ex = sm[t] - v;
        bstart[t] = ex;
        gcur[t] = ex;
    }
    if (t == 0) bstart[NB] = E;
}

__global__ __launch_bounds__(256) void bucket_scatter_kernel(const int* __restrict__ src,
                                                             const int* __restrict__ dst,
                                                             int* __restrict__ gcur,
                                                             uint2* __restrict__ staging,
                                                             int E, int NB) {
    __shared__ int hist[512];
    __shared__ int base[512];
    int t = threadIdx.x;
    for (int b = t; b < NB; b += 256) hist[b] = 0;
    __syncthreads();
    int s[16], d[16], r[16];
    int e0 = blockIdx.x * 4096;
    #pragma unroll
    for (int j = 0; j < 16; ++j) {
        int e = e0 + j * 256 + t;
        if (e < E) {
            s[j] = src[e];
            d[j] = dst[e];
            r[j] = atomicAdd(&hist[d[j] >> BSH], 1);
        } else d[j] = -1;
    }
    __syncthreads();
    for (int b = t; b < NB; b += 256) {
        int v = hist[b];
        base[b] = v ? atomicAdd(&gcur[b], v) : 0;
    }
    __syncthreads();
    #pragma unroll
    for (int j = 0; j < 16; ++j) {
        if (d[j] >= 0) {
            int b = d[j] >> BSH;
            staging[base[b] + r[j]] = make_uint2((unsigned)s[j], (unsigned)d[j]);
        }
    }
}

__global__ __launch_bounds__(256) void csr_build_kernel(const uint2* __restrict__ staging,
                                                        const int* __restrict__ bstart,
                                                        int* __restrict__ rp, int* __restrict__ csr,
                                                        int N, int E, int NB) {
    __shared__ int hist[256];
    __shared__ int sm[256];
    __shared__ int excl[256];
    __shared__ int cnt[256];
    int t = threadIdx.x;
    int b = blockIdx.x;
    int nbase = b << BSH;
    int s0 = bstart[b], e1 = bstart[b + 1];
    hist[t] = 0;
    __syncthreads();
    for (int i = s0 + t; i < e1; i += 256) {
        uint2 p = staging[i];
        atomicAdd(&hist[p.y & (BNODES - 1)], 1);
    }
    __syncthreads();
    int h = hist[t];
    sm[t] = h;
    __syncthreads();
    for (int off = 1; off < 256; off <<= 1) {
        int add = (t >= off) ? sm[t - off] : 0;
        __syncthreads();
        sm[t] += add;
        __syncthreads();
    }
    excl[t] = sm[t] - h;
    cnt[t] = 0;
    int n = nbase + t;
    if (n < N) rp[n] = s0 + (sm[t] - h);
    if (b == NB - 1 && t == 0) rp[N] = E;
    __syncthreads();
    for (int i = s0 + t; i < e1; i += 256) {
        uint2 p = staging[i];
        int dl = p.y & (BNODES - 1);
        int pos = s0 + excl[dl] + atomicAdd(&cnt[dl], 1);
        csr[pos] = (int)p.x;
    }
}

// ---------------- weight fp32 -> bf16 pack ----------------

__global__ void wconv_kernel(const float* __restrict__ W0, const float* __restrict__ W1,
                             const float* __restrict__ W2,
                             unsigned* __restrict__ O0, unsigned* __restrict__ O1,
                             unsigned* __restrict__ O2) {
    int id = blockIdx.x * blockDim.x + threadIdx.x;
    if (id >= 3 * 8192) return;
    int sel = id >> 13, l = id & 8191;
    const float* W = sel == 0 ? W0 : (sel == 1 ? W1 : W2);
    unsigned* O = sel == 0 ? O0 : (sel == 1 ? O1 : O2);
    O[l] = pack_bf2(W[2 * l], W[2 * l + 1]);
}

// ---------------- h0 = concat(deg, feat) in bf16 ----------------

__global__ void build_h0_kernel(const float* __restrict__ feat, const int* __restrict__ rp,
                                unsigned* __restrict__ h0, int N) {
    int id = blockIdx.x * blockDim.x + threadIdx.x;
    if (id >= N * 64) return;
    int n = id >> 6, c = id & 63;
    const float* fr = feat + (size_t)n * NRAW;
    float x, y;
    if (c == 0) {
        x = (float)(rp[n + 1] - rp[n]);
        y = fr[0];
    } else {
        x = fr[2 * c - 1];
        y = fr[2 * c];
    }
    h0[id] = pack_bf2(x, y);
}

// ---------------- fused GCN layer: mean-agg (into LDS) + MFMA GEMM + bias + relu ----------------
// h [N,128] bf16 (as uint pairs), Wb [128,128] bf16, out [N,128] bf16.
// 16x16x32 MFMA layouts: A/B frag lane holds [idx = lane&15][k = (lane>>4)*8 + j];
// C/D: col = lane&15, row = (lane>>4)*4 + reg.

__global__ __launch_bounds__(256) void gcn_layer_kernel(const unsigned* __restrict__ h,
                                                        unsigned* __restrict__ out,
                                                        const unsigned* __restrict__ Wb,
                                                        const float* __restrict__ bias,
                                                        const int* __restrict__ rp,
                                                        const int* __restrict__ csr, int N) {
    __shared__ unsigned Al[64 * APAD];
    __shared__ unsigned Wl[128 * APAD];
    int t = threadIdx.x;
    int n0 = blockIdx.x * 64;

    // stage W: 128 rows x 16 uint4
    #pragma unroll
    for (int c = 0; c < 8; ++c) {
        int f = c * 256 + t;
        int row = f >> 4, c4 = f & 15;
        uint4 v = ((const uint4*)Wb)[f];
        *(uint4*)&Wl[row * APAD + c4 * 4] = v;
    }

    int wv = t >> 6, lane = t & 63;

    // aggregation phase: wave wv handles nodes n0 + wv*16 .. +15
    for (int l = wv * 16; l < wv * 16 + 16; ++l) {
        int i = n0 + l;
        if (i >= N) break;
        int start = rp[i], end = rp[i + 1];
        int deg = end - start;
        unsigned res;
        if (deg == 0) {
            res = h[(size_t)i * 64 + lane];   // keep old h (exact)
        } else {
            float ax = 0.f, ay = 0.f;
            for (int e = start; e < end; e += 64) {
                int batch = min(end - e, 64);
                int mysrc = csr[e + ((lane < batch) ? lane : 0)];
                int j0 = 0;
                for (; j0 + 8 <= batch; j0 += 8) {
                    unsigned v[8];
                    #pragma unroll
                    for (int j = 0; j < 8; ++j) {
                        int sj = __builtin_amdgcn_readlane(mysrc, j0 + j);
                        v[j] = h[(size_t)sj * 64 + lane];
                    }
                    #pragma unroll
                    for (int j = 0; j < 8; ++j) { ax += bf_lo(v[j]); ay += bf_hi(v[j]); }
                }
                for (; j0 < batch; ++j0) {
                    int sj = __builtin_amdgcn_readlane(mysrc, j0);
                    unsigned v = h[(size_t)sj * 64 + lane];
                    ax += bf_lo(v); ay += bf_hi(v);
                }
            }
            float inv = 1.f / (float)deg;
            res = pack_bf2(ax * inv, ay * inv);
        }
        Al[l * APAD + lane] = res;
    }
    __syncthreads();

    // GEMM phase
    int m = lane & 15, q = lane >> 4;
    floatx4 acc[8];
    #pragma unroll
    for (int ot = 0; ot < 8; ++ot) acc[ot] = (floatx4)(0.f);

    #pragma unroll
    for (int kt = 0; kt < 4; ++kt) {
        short8 af = *(const short8*)&Al[(wv * 16 + m) * APAD + kt * 16 + q * 4];
        #pragma unroll
        for (int ot = 0; ot < 8; ++ot) {
            short8 bf = *(const short8*)&Wl[(ot * 16 + m) * APAD + kt * 16 + q * 4];
            acc[ot] = __builtin_amdgcn_mfma_f32_16x16x32_bf16(af, bf, acc[ot], 0, 0, 0);
        }
    }

    unsigned short* oh = (unsigned short*)out;
    #pragma unroll
    for (int ot = 0; ot < 8; ++ot) {
        int o = ot * 16 + m;
        float bv = bias[o];
        #pragma unroll
        for (int r = 0; r < 4; ++r) {
            int n = n0 + wv * 16 + q * 4 + r;
            if (n < N) {
                float v = fmaxf(acc[ot][r] + bv, 0.f);
                unsigned bx = __float_as_uint(v);
                bx += 0x7fffu + ((bx >> 16) & 1u);
                oh[(size_t)n * 128 + o] = (unsigned short)(bx >> 16);
            }
        }
    }
}

// ---------------- graph mean-pool ----------------

__global__ void pool_kernel(const unsigned* __restrict__ h, const int* __restrict__ gid,
                            float* __restrict__ hg, int N) {
    int c = threadIdx.x & 63;
    int half = threadIdx.x >> 6;
    int n0 = blockIdx.x * 512;
    int nend = min(n0 + 512, N);
    float ax = 0.f, ay = 0.f;
    int cur = -1;
    for (int n = n0 + half; n < nend; n += 4) {
        int g = gid[n];
        if (g != cur) {
            if (cur >= 0) {
                atomicAdd(&hg[cur * HID + 2 * c], ax);
                atomicAdd(&hg[cur * HID + 2 * c + 1], ay);
            }
            ax = ay = 0.f;
            cur = g;
        }
        unsigned v = h[n * 64 + c];
        ax += bf_lo(v); ay += bf_hi(v);
    }
    if (cur >= 0) {
        atomicAdd(&hg[cur * HID + 2 * c], ax);
        atomicAdd(&hg[cur * HID + 2 * c + 1], ay);
    }
}

__global__ void counts_kernel(const int* __restrict__ gid, float* __restrict__ counts, int N) {
    int t = blockIdx.x * blockDim.x + threadIdx.x;
    int n0 = t * 64;
    if (n0 >= N) return;
    int nend = min(n0 + 64, N);
    int cur = gid[n0];
    float c = 0.f;
    for (int n = n0; n < nend; ++n) {
        int g = gid[n];
        if (g != cur) { atomicAdd(&counts[cur], c); c = 0.f; cur = g; }
        c += 1.f;
    }
    atomicAdd(&counts[cur], c);
}

// ---------------- classifier head (fp32) ----------------

__global__ void cls_kernel(const float* __restrict__ in, const float* __restrict__ W,
                           const float* __restrict__ b, float* __restrict__ out,
                           const float* __restrict__ counts, int G) {
    int id = blockIdx.x * blockDim.x + threadIdx.x;
    if (id >= G * HID) return;
    int g = id >> 7, o = id & 127;
    const float* row = in + g * HID;
    const float* w = W + o * HID;
    float s = 0.f;
    #pragma unroll 8
    for (int k = 0; k < HID; ++k) s = fmaf(row[k], w[k], s);
    float inv = 1.f;
    if (counts) inv = 1.f / fmaxf(counts[g], 1.f);
    out[id] = s * inv + b[o];
}

__global__ void cls3_kernel(const float* __restrict__ in, const float* __restrict__ W,
                            const float* __restrict__ b, float* __restrict__ out, int G) {
    int g = blockIdx.x * blockDim.x + threadIdx.x;
    if (g >= G) return;
    const float* row = in + g * HID;
    float s = 0.f;
    #pragma unroll 8
    for (int k = 0; k < HID; ++k) s = fmaf(row[k], W[k], s);
    out[g] = s + b[0];
}

// ---------------- launch ----------------

extern "C" void kernel_launch(void* const* d_in, const int* in_sizes, int n_in,
                              void* d_out, int out_size, void* d_ws, size_t ws_size,
                              hipStream_t stream) {
    const float* feat = (const float*)d_in[0];
    const int* src    = (const int*)d_in[1];
    const int* dst    = (const int*)d_in[2];
    const int* gid    = (const int*)d_in[3];
    const float* W0  = (const float*)d_in[5];
    const float* b0  = (const float*)d_in[6];
    const float* W1  = (const float*)d_in[7];
    const float* b1  = (const float*)d_in[8];
    const float* W2  = (const float*)d_in[9];
    const float* b2  = (const float*)d_in[10];
    const float* Wc1 = (const float*)d_in[11];
    const float* bc1 = (const float*)d_in[12];
    const float* Wc2 = (const float*)d_in[13];
    const float* bc2 = (const float*)d_in[14];

    const int N = in_sizes[3];
    const int E = in_sizes[1];
    const int G = out_size;
    const int NB = (N + BNODES - 1) >> BSH;   // 391 for N=100000 (must be <= 512)

    char* ws = (char*)d_ws;
    size_t off = 0;
    auto alloc = [&](size_t bytes) { void* p = ws + off; off += (bytes + 255) & ~size_t(255); return p; };
    unsigned* hA     = (unsigned*)alloc((size_t)N * 64 * 4);
    unsigned* hB     = (unsigned*)alloc((size_t)N * 64 * 4);
    uint2* staging   = (uint2*)alloc((size_t)E * 8);
    int* csr         = (int*)alloc((size_t)E * 4);
    int* rp          = (int*)alloc((size_t)(N + 1) * 4);
    int* gbucket     = (int*)alloc(512 * 4);
    int* bstart      = (int*)alloc(513 * 4);
    int* gcur        = (int*)alloc(512 * 4);
    unsigned* Wb0    = (unsigned*)alloc(8192 * 4);
    unsigned* Wb1    = (unsigned*)alloc(8192 * 4);
    unsigned* Wb2    = (unsigned*)alloc(8192 * 4);
    float* hg        = (float*)alloc((size_t)G * HID * 4);
    float* hg1      = (float*)alloc((size_t)G * HID * 4);
    float* hg2      = (float*)alloc((size_t)G * HID * 4);
    float* counts   = (float*)alloc((size_t)G * 4);

    hipMemsetAsync(gbucket, 0, 512 * 4, stream);
    hipMemsetAsync(hg, 0, (size_t)G * HID * 4, stream);
    hipMemsetAsync(counts, 0, (size_t)G * 4, stream);

    int gE = (E + 4095) / 4096;
    bucket_count_kernel<<<gE, 256, 0, stream>>>(dst, gbucket, E, NB);
    bucket_scan_kernel<<<1, 512, 0, stream>>>(gbucket, bstart, gcur, NB, E);
    bucket_scatter_kernel<<<gE, 256, 0, stream>>>(src, dst, gcur, staging, E, NB);
    csr_build_kernel<<<NB, 256, 0, stream>>>(staging, bstart, rp, csr, N, E, NB);

    wconv_kernel<<<(3 * 8192 + 255) / 256, 256, 0, stream>>>(W0, W1, W2, Wb0, Wb1, Wb2);
    build_h0_kernel<<<(N * 64 + 255) / 256, 256, 0, stream>>>(feat, rp, hA, N);

    int layer_grid = (N + 63) / 64;
    gcn_layer_kernel<<<layer_grid, 256, 0, stream>>>(hA, hB, Wb0, b0, rp, csr, N);
    gcn_layer_kernel<<<layer_grid, 256, 0, stream>>>(hB, hA, Wb1, b1, rp, csr, N);
    gcn_layer_kernel<<<layer_grid, 256, 0, stream>>>(hA, hB, Wb2, b2, rp, csr, N);

    pool_kernel<<<(N + 511) / 512, 256, 0, stream>>>(hB, gid, hg, N);
    counts_kernel<<<(((N + 63) / 64) + 255) / 256, 256, 0, stream>>>(gid, counts, N);

    cls_kernel<<<(G * HID + 255) / 256, 256, 0, stream>>>(hg, Wc1, bc1, hg1, counts, G);
    cls_kernel<<<(G * HID + 255) / 256, 256, 0, stream>>>(hg1, Wc1, bc1, hg2, nullptr, G);
    cls3_kernel<<<1, 128, 0, stream>>>(hg2, Wc2, bc2, (float*)d_out, G);
}

// Round 4
// 551.502 us; speedup vs baseline: 1.2966x; 1.2966x over previous
//
#include <hip/hip_runtime.h>
#include <hip/hip_bf16.h>

#define HID 128
#define NRAW 127
#define BSH 8          // 256 nodes per bucket
#define BNODES 256
#define APAD 68        // LDS row pitch in u32 (16B-aligned, breaks pow2 stride)

typedef __attribute__((ext_vector_type(8))) short short8;
typedef __attribute__((ext_vector_type(4))) float floatx4;

__device__ inline unsigned pack_bf2(float x, float y) {
    unsigned bx = __float_as_uint(x);
    unsigned by = __float_as_uint(y);
    bx += 0x7fffu + ((bx >> 16) & 1u);   // RNE
    by += 0x7fffu + ((by >> 16) & 1u);
    return (bx >> 16) | (by & 0xffff0000u);
}
__device__ inline float bf_lo(unsigned u) { return __uint_as_float(u << 16); }
__device__ inline float bf_hi(unsigned u) { return __uint_as_float(u & 0xffff0000u); }

// ---------------- init: zeros + weight bf16 pack (replaces 3 memsets + wconv) ----------------

__global__ void init_kernel(const float* __restrict__ W0, const float* __restrict__ W1,
                            const float* __restrict__ W2,
                            unsigned* __restrict__ O0, unsigned* __restrict__ O1,
                            unsigned* __restrict__ O2,
                            int* __restrict__ gbucket, float* __restrict__ hg,
                            float* __restrict__ counts, int G) {
    int id = blockIdx.x * blockDim.x + threadIdx.x;
    if (id < 512) gbucket[id] = 0;
    if (id < G * HID) hg[id] = 0.f;
    if (id < G) counts[id] = 0.f;
    if (id < 3 * 8192) {
        int sel = id >> 13, l = id & 8191;
        const float* W = sel == 0 ? W0 : (sel == 1 ? W1 : W2);
        unsigned* O = sel == 0 ? O0 : (sel == 1 ? O1 : O2);
        O[l] = pack_bf2(W[2 * l], W[2 * l + 1]);
    }
}

// ---------------- CSR build: bucketed 2-phase counting sort ----------------

__global__ __launch_bounds__(256) void bucket_count_kernel(const int* __restrict__ dst,
                                                           int* __restrict__ gbucket,
                                                           int E, int NB) {
    __shared__ int hist[512];
    int t = threadIdx.x;
    for (int b = t; b < NB; b += 256) hist[b] = 0;
    __syncthreads();
    int base = blockIdx.x * 4096;
    #pragma unroll
    for (int j = 0; j < 16; ++j) {
        int e = base + j * 256 + t;
        if (e < E) atomicAdd(&hist[dst[e] >> BSH], 1);
    }
    __syncthreads();
    for (int b = t; b < NB; b += 256) {
        int v = hist[b];
        if (v) atomicAdd(&gbucket[b], v);
    }
}

__global__ void bucket_scan_kernel(const int* __restrict__ gbucket, int* __restrict__ bstart,
                                   int* __restrict__ gcur, int NB, int E) {
    __shared__ int sm[512];
    int t = threadIdx.x;
    int v = (t < NB) ? gbucket[t] : 0;
    sm[t] = v;
    __syncthreads();
    for (int off = 1; off < 512; off <<= 1) {
        int add = (t >= off) ? sm[t - off] : 0;
        __syncthreads();
        sm[t] += add;
        __syncthreads();
    }
    if (t < NB) {
        int ex = sm[t] - v;
        bstart[t] = ex;
        gcur[t] = ex;
    }
    if (t == 0) bstart[NB] = E;
}

__global__ __launch_bounds__(256) void bucket_scatter_kernel(const int* __restrict__ src,
                                                             const int* __restrict__ dst,
                                                             int* __restrict__ gcur,
                                                             uint2* __restrict__ staging,
                                                             int E, int NB) {
    __shared__ int hist[512];
    __shared__ int base[512];
    int t = threadIdx.x;
    for (int b = t; b < NB; b += 256) hist[b] = 0;
    __syncthreads();
    int s[16], d[16], r[16];
    int e0 = blockIdx.x * 4096;
    #pragma unroll
    for (int j = 0; j < 16; ++j) {
        int e = e0 + j * 256 + t;
        if (e < E) {
            s[j] = src[e];
            d[j] = dst[e];
            r[j] = atomicAdd(&hist[d[j] >> BSH], 1);
        } else d[j] = -1;
    }
    __syncthreads();
    for (int b = t; b < NB; b += 256) {
        int v = hist[b];
        base[b] = v ? atomicAdd(&gcur[b], v) : 0;
    }
    __syncthreads();
    #pragma unroll
    for (int j = 0; j < 16; ++j) {
        if (d[j] >= 0) {
            int b = d[j] >> BSH;
            staging[base[b] + r[j]] = make_uint2((unsigned)s[j], (unsigned)d[j]);
        }
    }
}

__global__ __launch_bounds__(256) void csr_build_kernel(const uint2* __restrict__ staging,
                                                        const int* __restrict__ bstart,
                                                        int* __restrict__ rp, int* __restrict__ csr,
                                                        int N, int E, int NB) {
    __shared__ int hist[256];
    __shared__ int sm[256];
    __shared__ int excl[256];
    __shared__ int cnt[256];
    int t = threadIdx.x;
    int b = blockIdx.x;
    int nbase = b << BSH;
    int s0 = bstart[b], e1 = bstart[b + 1];
    hist[t] = 0;
    __syncthreads();
    for (int i = s0 + t; i < e1; i += 256) {
        uint2 p = staging[i];
        atomicAdd(&hist[p.y & (BNODES - 1)], 1);
    }
    __syncthreads();
    int h = hist[t];
    sm[t] = h;
    __syncthreads();
    for (int off = 1; off < 256; off <<= 1) {
        int add = (t >= off) ? sm[t - off] : 0;
        __syncthreads();
        sm[t] += add;
        __syncthreads();
    }
    excl[t] = sm[t] - h;
    cnt[t] = 0;
    int n = nbase + t;
    if (n < N) rp[n] = s0 + (sm[t] - h);
    if (b == NB - 1 && t == 0) rp[N] = E;
    __syncthreads();
    for (int i = s0 + t; i < e1; i += 256) {
        uint2 p = staging[i];
        int dl = p.y & (BNODES - 1);
        int pos = s0 + excl[dl] + atomicAdd(&cnt[dl], 1);
        csr[pos] = (int)p.x;
    }
}

// ---------------- h0 = concat(deg, feat) in bf16 ----------------

__global__ void build_h0_kernel(const float* __restrict__ feat, const int* __restrict__ rp,
                                unsigned* __restrict__ h0, int N) {
    int id = blockIdx.x * blockDim.x + threadIdx.x;
    if (id >= N * 64) return;
    int n = id >> 6, c = id & 63;
    const float* fr = feat + (size_t)n * NRAW;
    float x, y;
    if (c == 0) {
        x = (float)(rp[n + 1] - rp[n]);
        y = fr[0];
    } else {
        x = fr[2 * c - 1];
        y = fr[2 * c];
    }
    h0[id] = pack_bf2(x, y);
}

// ---------------- aggregation: one wave per node, uint2 gather, scalar-addressed ----------------

__global__ __launch_bounds__(256) void agg_kernel(const unsigned* __restrict__ h,
                                                  unsigned* __restrict__ agg,
                                                  const int* __restrict__ rp,
                                                  const int* __restrict__ csr, int N) {
    int wv = threadIdx.x >> 6, lane = threadIdx.x & 63;
    int i = blockIdx.x * 4 + wv;
    if (i >= N) return;
    int l5 = lane & 31;
    int half = lane >> 5;
    int start = rp[i], end = rp[i + 1];
    int deg = end - start;
    const uint2* h2 = (const uint2*)h;
    uint2* o2 = (uint2*)agg;
    if (deg == 0) {
        if (half == 0) o2[(size_t)i * 32 + l5] = h2[(size_t)i * 32 + l5];
        return;
    }
    float a0 = 0.f, a1 = 0.f, a2 = 0.f, a3 = 0.f;
    int vbase = l5 * 2;   // u32 offset within row (lane covers u32 cols 2*l5, 2*l5+1)
    int e = start;
    while (e < end) {
        int rem = end - e;
        if (rem >= 16) {
            int idx = csr[e + (lane & 15)];
            int woff[8];
            uint2 v[8];
            #pragma unroll
            for (int p = 0; p < 8; ++p) {
                int s0 = __builtin_amdgcn_readlane(idx, 2 * p);
                int s1 = __builtin_amdgcn_readlane(idx, 2 * p + 1);
                woff[p] = (half ? s1 : s0) * 64 + vbase;
            }
            #pragma unroll
            for (int p = 0; p < 8; ++p) v[p] = *(const uint2*)&h[woff[p]];
            #pragma unroll
            for (int p = 0; p < 8; ++p) {
                a0 += bf_lo(v[p].x); a1 += bf_hi(v[p].x);
                a2 += bf_lo(v[p].y); a3 += bf_hi(v[p].y);
            }
            e += 16;
        } else {
            int idx = csr[e + min(lane & 15, rem - 1)];
            #pragma unroll
            for (int p = 0; p < 8; ++p) {
                if (2 * p >= rem) break;
                int k1 = min(2 * p + 1, rem - 1);
                int s0 = __builtin_amdgcn_readlane(idx, 2 * p);
                int s1 = __builtin_amdgcn_readlane(idx, k1);
                uint2 v = *(const uint2*)&h[(half ? s1 : s0) * 64 + vbase];
                if (2 * p + 1 >= rem) {    // odd tail: upper half-row invalid
                    if (half) { v.x = 0u; v.y = 0u; }
                }
                a0 += bf_lo(v.x); a1 += bf_hi(v.x);
                a2 += bf_lo(v.y); a3 += bf_hi(v.y);
            }
            e = end;
        }
    }
    // cross-half reduce (lanes l and l^32 hold same columns, different neighbor subsets)
    a0 += __shfl_xor(a0, 32);
    a1 += __shfl_xor(a1, 32);
    a2 += __shfl_xor(a2, 32);
    a3 += __shfl_xor(a3, 32);
    if (half == 0) {
        float inv = 1.f / (float)deg;
        uint2 r;
        r.x = pack_bf2(a0 * inv, a1 * inv);
        r.y = pack_bf2(a2 * inv, a3 * inv);
        o2[(size_t)i * 32 + l5] = r;
    }
}

// ---------------- GEMM: out = relu(A @ W^T + b) via MFMA bf16, B-frags from global ----------------
// A [N,128] bf16, Wb [128,128] bf16 (row-major over k), out bf16.
// 16x16x32 layouts: A/B frag lane holds [idx = lane&15][k = (lane>>4)*8 + j];
// C/D: col = lane&15, row = (lane>>4)*4 + reg.

__global__ __launch_bounds__(256) void mfma_gemm_kernel(const unsigned* __restrict__ A,
                                                        unsigned* __restrict__ out,
                                                        const unsigned* __restrict__ Wb,
                                                        const float* __restrict__ bias, int N) {
    __shared__ unsigned Al[64 * APAD];
    int t = threadIdx.x;
    int n0 = blockIdx.x * 64;
    // stage A: 64 rows x 16 uint4
    #pragma unroll
    for (int c = 0; c < 4; ++c) {
        int f = c * 256 + t;
        int row = f >> 4, c4 = f & 15;
        int n = n0 + row;
        uint4 v = make_uint4(0u, 0u, 0u, 0u);
        if (n < N) v = ((const uint4*)A)[(size_t)n * 16 + c4];
        *(uint4*)&Al[row * APAD + c4 * 4] = v;
    }
    __syncthreads();

    int wv = t >> 6, lane = t & 63;
    int m = lane & 15, q = lane >> 4;
    floatx4 acc[8];
    #pragma unroll
    for (int ot = 0; ot < 8; ++ot) acc[ot] = (floatx4)(0.f);

    #pragma unroll
    for (int kt = 0; kt < 4; ++kt) {
        short8 af = *(const short8*)&Al[(wv * 16 + m) * APAD + kt * 16 + q * 4];
        short8 bf[8];
        #pragma unroll
        for (int ot = 0; ot < 8; ++ot)
            bf[ot] = *(const short8*)&Wb[(ot * 16 + m) * 64 + kt * 16 + q * 4];
        #pragma unroll
        for (int ot = 0; ot < 8; ++ot)
            acc[ot] = __builtin_amdgcn_mfma_f32_16x16x32_bf16(af, bf[ot], acc[ot], 0, 0, 0);
    }

    unsigned short* oh = (unsigned short*)out;
    #pragma unroll
    for (int ot = 0; ot < 8; ++ot) {
        int o = ot * 16 + m;
        float bv = bias[o];
        #pragma unroll
        for (int r = 0; r < 4; ++r) {
            int n = n0 + wv * 16 + q * 4 + r;
            if (n < N) {
                float v = fmaxf(acc[ot][r] + bv, 0.f);
                unsigned bx = __float_as_uint(v);
                bx += 0x7fffu + ((bx >> 16) & 1u);
                oh[(size_t)n * 128 + o] = (unsigned short)(bx >> 16);
            }
        }
    }
}

// ---------------- graph mean-pool ----------------

__global__ void pool_kernel(const unsigned* __restrict__ h, const int* __restrict__ gid,
                            float* __restrict__ hg, int N) {
    int c = threadIdx.x & 63;
    int half = threadIdx.x >> 6;
    int n0 = blockIdx.x * 512;
    int nend = min(n0 + 512, N);
    float ax = 0.f, ay = 0.f;
    int cur = -1;
    for (int n = n0 + half; n < nend; n += 4) {
        int g = gid[n];
        if (g != cur) {
            if (cur >= 0) {
                atomicAdd(&hg[cur * HID + 2 * c], ax);
                atomicAdd(&hg[cur * HID + 2 * c + 1], ay);
            }
            ax = ay = 0.f;
            cur = g;
        }
        unsigned v = h[(size_t)n * 64 + c];
        ax += bf_lo(v); ay += bf_hi(v);
    }
    if (cur >= 0) {
        atomicAdd(&hg[cur * HID + 2 * c], ax);
        atomicAdd(&hg[cur * HID + 2 * c + 1], ay);
    }
}

__global__ void counts_kernel(const int* __restrict__ gid, float* __restrict__ counts, int N) {
    int t = blockIdx.x * blockDim.x + threadIdx.x;
    int n0 = t * 64;
    if (n0 >= N) return;
    int nend = min(n0 + 64, N);
    int cur = gid[n0];
    float c = 0.f;
    for (int n = n0; n < nend; ++n) {
        int g = gid[n];
        if (g != cur) { atomicAdd(&counts[cur], c); c = 0.f; cur = g; }
        c += 1.f;
    }
    atomicAdd(&counts[cur], c);
}

// ---------------- fused classifier head (fp32), one block per graph ----------------
// hg_sum -> /count -> (Wc1 x + bc1) twice (no activation) -> Wc2 dot + bc2

__global__ __launch_bounds__(128) void cls_fused_kernel(const float* __restrict__ hg,
                                                        const float* __restrict__ counts,
                                                        const float* __restrict__ Wc1,
                                                        const float* __restrict__ bc1,
                                                        const float* __restrict__ Wc2,
                                                        const float* __restrict__ bc2,
                                                        float* __restrict__ out, int G) {
    __shared__ float x[128];
    __shared__ float y[128];
    __shared__ float red[128];
    int g = blockIdx.x, t = threadIdx.x;
    float inv = 1.f / fmaxf(counts[g], 1.f);
    x[t] = hg[g * HID + t] * inv;
    __syncthreads();
    const float4* w4 = (const float4*)(Wc1 + t * HID);
    float s = 0.f;
    #pragma unroll
    for (int k4 = 0; k4 < 32; ++k4) {
        float4 w = w4[k4];
        s += x[k4 * 4] * w.x + x[k4 * 4 + 1] * w.y + x[k4 * 4 + 2] * w.z + x[k4 * 4 + 3] * w.w;
    }
    y[t] = s + bc1[t];
    __syncthreads();
    float s2 = 0.f;
    #pragma unroll
    for (int k4 = 0; k4 < 32; ++k4) {
        float4 w = w4[k4];
        s2 += y[k4 * 4] * w.x + y[k4 * 4 + 1] * w.y + y[k4 * 4 + 2] * w.z + y[k4 * 4 + 3] * w.w;
    }
    red[t] = (s2 + bc1[t]) * Wc2[t];
    __syncthreads();
    if (t < 64) {
        float r = red[t] + red[t + 64];
        #pragma unroll
        for (int off = 32; off > 0; off >>= 1) r += __shfl_down(r, off);
        if (t == 0) out[g] = r + bc2[0];
    }
}

// ---------------- launch ----------------

extern "C" void kernel_launch(void* const* d_in, const int* in_sizes, int n_in,
                              void* d_out, int out_size, void* d_ws, size_t ws_size,
                              hipStream_t stream) {
    const float* feat = (const float*)d_in[0];
    const int* src    = (const int*)d_in[1];
    const int* dst    = (const int*)d_in[2];
    const int* gid    = (const int*)d_in[3];
    const float* W0  = (const float*)d_in[5];
    const float* b0  = (const float*)d_in[6];
    const float* W1  = (const float*)d_in[7];
    const float* b1  = (const float*)d_in[8];
    const float* W2  = (const float*)d_in[9];
    const float* b2  = (const float*)d_in[10];
    const float* Wc1 = (const float*)d_in[11];
    const float* bc1 = (const float*)d_in[12];
    const float* Wc2 = (const float*)d_in[13];
    const float* bc2 = (const float*)d_in[14];

    const int N = in_sizes[3];
    const int E = in_sizes[1];
    const int G = out_size;
    const int NB = (N + BNODES - 1) >> BSH;   // 391 for N=100000 (must be <= 512)

    char* ws = (char*)d_ws;
    size_t off = 0;
    auto alloc = [&](size_t bytes) { void* p = ws + off; off += (bytes + 255) & ~size_t(255); return p; };
    unsigned* hA     = (unsigned*)alloc((size_t)N * 64 * 4);
    unsigned* hB     = (unsigned*)alloc((size_t)N * 64 * 4);
    unsigned* aggbuf = (unsigned*)alloc((size_t)N * 64 * 4);
    uint2* staging   = (uint2*)alloc((size_t)E * 8);
    int* csr         = (int*)alloc((size_t)E * 4);
    int* rp          = (int*)alloc((size_t)(N + 1) * 4);
    int* gbucket     = (int*)alloc(512 * 4);
    int* bstart      = (int*)alloc(513 * 4);
    int* gcur        = (int*)alloc(512 * 4);
    unsigned* Wb0    = (unsigned*)alloc(8192 * 4);
    unsigned* Wb1    = (unsigned*)alloc(8192 * 4);
    unsigned* Wb2    = (unsigned*)alloc(8192 * 4);
    float* hg        = (float*)alloc((size_t)G * HID * 4);
    float* counts    = (float*)alloc((size_t)G * 4);

    init_kernel<<<96, 256, 0, stream>>>(W0, W1, W2, Wb0, Wb1, Wb2, gbucket, hg, counts, G);

    int gE = (E + 4095) / 4096;
    bucket_count_kernel<<<gE, 256, 0, stream>>>(dst, gbucket, E, NB);
    bucket_scan_kernel<<<1, 512, 0, stream>>>(gbucket, bstart, gcur, NB, E);
    bucket_scatter_kernel<<<gE, 256, 0, stream>>>(src, dst, gcur, staging, E, NB);
    csr_build_kernel<<<NB, 256, 0, stream>>>(staging, bstart, rp, csr, N, E, NB);

    build_h0_kernel<<<(N * 64 + 255) / 256, 256, 0, stream>>>(feat, rp, hA, N);

    int agg_grid = (N + 3) / 4;
    int gemm_grid = (N + 63) / 64;

    agg_kernel<<<agg_grid, 256, 0, stream>>>(hA, aggbuf, rp, csr, N);
    mfma_gemm_kernel<<<gemm_grid, 256, 0, stream>>>(aggbuf, hB, Wb0, b0, N);

    agg_kernel<<<agg_grid, 256, 0, stream>>>(hB, aggbuf, rp, csr, N);
    mfma_gemm_kernel<<<gemm_grid, 256, 0, stream>>>(aggbuf, hA, Wb1, b1, N);

    agg_kernel<<<agg_grid, 256, 0, stream>>>(hA, aggbuf, rp, csr, N);
    mfma_gemm_kernel<<<gemm_grid, 256, 0, stream>>>(aggbuf, hB, Wb2, b2, N);

    pool_kernel<<<(N + 511) / 512, 256, 0, stream>>>(hB, gid, hg, N);
    counts_kernel<<<(((N + 63) / 64) + 255) / 256, 256, 0, stream>>>(gid, counts, N);

    cls_fused_kernel<<<G, 128, 0, stream>>>(hg, counts, Wc1, bc1, Wc2, bc2, (float*)d_out, G);
}

// Round 5
// 509.102 us; speedup vs baseline: 1.4046x; 1.0833x over previous
//
#include <hip/hip_runtime.h>
#include <hip/hip_bf16.h>

#define HID 128
#define NRAW 127
#define BSH 8          // 256 nodes per bucket
#define BNODES 256
#define APAD 68        // LDS row pitch in u32 (16B-aligned, breaks pow2 stride)

typedef __attribute__((ext_vector_type(8))) short short8;
typedef __attribute__((ext_vector_type(4))) float floatx4;
typedef __attribute__((ext_vector_type(2))) float floatx2;

__device__ inline unsigned pack_bf2(float x, float y) {
    unsigned bx = __float_as_uint(x);
    unsigned by = __float_as_uint(y);
    bx += 0x7fffu + ((bx >> 16) & 1u);   // RNE
    by += 0x7fffu + ((by >> 16) & 1u);
    return (bx >> 16) | (by & 0xffff0000u);
}
__device__ inline float bf_lo(unsigned u) { return __uint_as_float(u << 16); }
__device__ inline float bf_hi(unsigned u) { return __uint_as_float(u & 0xffff0000u); }

// ---------------- init: zeros + weight bf16 pack ----------------

__global__ void init_kernel(const float* __restrict__ W0, const float* __restrict__ W1,
                            const float* __restrict__ W2,
                            unsigned* __restrict__ O0, unsigned* __restrict__ O1,
                            unsigned* __restrict__ O2,
                            int* __restrict__ gbucket, float* __restrict__ hg,
                            float* __restrict__ counts, int G) {
    int id = blockIdx.x * blockDim.x + threadIdx.x;
    if (id < 512) gbucket[id] = 0;
    if (id < G * HID) hg[id] = 0.f;
    if (id < G) counts[id] = 0.f;
    if (id < 3 * 8192) {
        int sel = id >> 13, l = id & 8191;
        const float* W = sel == 0 ? W0 : (sel == 1 ? W1 : W2);
        unsigned* O = sel == 0 ? O0 : (sel == 1 ? O1 : O2);
        O[l] = pack_bf2(W[2 * l], W[2 * l + 1]);
    }
}

// ---------------- CSR build: bucketed 2-phase counting sort ----------------

__global__ __launch_bounds__(256) void bucket_count_kernel(const int* __restrict__ dst,
                                                           int* __restrict__ gbucket,
                                                           int E, int NB) {
    __shared__ int hist[512];
    int t = threadIdx.x;
    for (int b = t; b < NB; b += 256) hist[b] = 0;
    __syncthreads();
    int base = blockIdx.x * 4096;
    #pragma unroll
    for (int j = 0; j < 16; ++j) {
        int e = base + j * 256 + t;
        if (e < E) atomicAdd(&hist[dst[e] >> BSH], 1);
    }
    __syncthreads();
    for (int b = t; b < NB; b += 256) {
        int v = hist[b];
        if (v) atomicAdd(&gbucket[b], v);
    }
}

__global__ void bucket_scan_kernel(const int* __restrict__ gbucket, int* __restrict__ bstart,
                                   int* __restrict__ gcur, int NB, int E) {
    __shared__ int sm[512];
    int t = threadIdx.x;
    int v = (t < NB) ? gbucket[t] : 0;
    sm[t] = v;
    __syncthreads();
    for (int off = 1; off < 512; off <<= 1) {
        int add = (t >= off) ? sm[t - off] : 0;
        __syncthreads();
        sm[t] += add;
        __syncthreads();
    }
    if (t < NB) {
        int ex = sm[t] - v;
        bstart[t] = ex;
        gcur[t] = ex;
    }
    if (t == 0) bstart[NB] = E;
}

__global__ __launch_bounds__(256) void bucket_scatter_kernel(const int* __restrict__ src,
                                                             const int* __restrict__ dst,
                                                             int* __restrict__ gcur,
                                                             uint2* __restrict__ staging,
                                                             int E, int NB) {
    __shared__ int hist[512];
    __shared__ int base[512];
    int t = threadIdx.x;
    for (int b = t; b < NB; b += 256) hist[b] = 0;
    __syncthreads();
    int s[16], d[16], r[16];
    int e0 = blockIdx.x * 4096;
    #pragma unroll
    for (int j = 0; j < 16; ++j) {
        int e = e0 + j * 256 + t;
        if (e < E) {
            s[j] = src[e];
            d[j] = dst[e];
            r[j] = atomicAdd(&hist[d[j] >> BSH], 1);
        } else d[j] = -1;
    }
    __syncthreads();
    for (int b = t; b < NB; b += 256) {
        int v = hist[b];
        base[b] = v ? atomicAdd(&gcur[b], v) : 0;
    }
    __syncthreads();
    #pragma unroll
    for (int j = 0; j < 16; ++j) {
        if (d[j] >= 0) {
            int b = d[j] >> BSH;
            staging[base[b] + r[j]] = make_uint2((unsigned)s[j], (unsigned)d[j]);
        }
    }
}

__global__ __launch_bounds__(256) void csr_build_kernel(const uint2* __restrict__ staging,
                                                        const int* __restrict__ bstart,
                                                        int* __restrict__ rp, int* __restrict__ csr,
                                                        int N, int E, int NB) {
    __shared__ int hist[256];
    __shared__ int sm[256];
    __shared__ int excl[256];
    __shared__ int cnt[256];
    int t = threadIdx.x;
    int b = blockIdx.x;
    int nbase = b << BSH;
    int s0 = bstart[b], e1 = bstart[b + 1];
    hist[t] = 0;
    __syncthreads();
    for (int i = s0 + t; i < e1; i += 256) {
        uint2 p = staging[i];
        atomicAdd(&hist[p.y & (BNODES - 1)], 1);
    }
    __syncthreads();
    int h = hist[t];
    sm[t] = h;
    __syncthreads();
    for (int off = 1; off < 256; off <<= 1) {
        int add = (t >= off) ? sm[t - off] : 0;
        __syncthreads();
        sm[t] += add;
        __syncthreads();
    }
    excl[t] = sm[t] - h;
    cnt[t] = 0;
    int n = nbase + t;
    if (n < N) rp[n] = s0 + (sm[t] - h);
    if (b == NB - 1 && t == 0) rp[N] = E;
    __syncthreads();
    for (int i = s0 + t; i < e1; i += 256) {
        uint2 p = staging[i];
        int dl = p.y & (BNODES - 1);
        int pos = s0 + excl[dl] + atomicAdd(&cnt[dl], 1);
        csr[pos] = (int)p.x;
    }
}

// ---------------- h0 in fp8 (col0 zeroed) + exact degf ----------------

__global__ void build_h0_kernel(const float* __restrict__ feat, const int* __restrict__ rp,
                                unsigned* __restrict__ h8, float* __restrict__ degf, int N) {
    int id = blockIdx.x * blockDim.x + threadIdx.x;
    if (id >= N * 32) return;
    int n = id >> 5, c = id & 31;
    const float* fr = feat + (size_t)n * NRAW;
    float f0, f1, f2, f3;
    if (c == 0) {
        f0 = 0.f;          // deg column handled exactly via degf in layer-0 agg
        f1 = fr[0]; f2 = fr[1]; f3 = fr[2];
    } else {
        int b = 4 * c - 1;
        f0 = fr[b]; f1 = fr[b + 1]; f2 = fr[b + 2]; f3 = fr[b + 3];
    }
    unsigned w = __builtin_amdgcn_cvt_pk_fp8_f32(f0, f1, 0, false);
    w = __builtin_amdgcn_cvt_pk_fp8_f32(f2, f3, w, true);
    h8[id] = w;
    if (c == 0) degf[n] = (float)(rp[n + 1] - rp[n]);
}

// ---------------- aggregation: fp8 gather, one wave per node ----------------
// h8 [N][32] u32 (=128 fp8 cols). out bf16 [N][64] u32. If degf != null (layer 0),
// col0 of the mean is computed exactly from degf.

__global__ __launch_bounds__(256) void agg_fp8_kernel(const unsigned* __restrict__ h8,
                                                      unsigned* __restrict__ agg,
                                                      const int* __restrict__ rp,
                                                      const int* __restrict__ csr,
                                                      const float* __restrict__ degf, int N) {
    int wv = threadIdx.x >> 6, lane = threadIdx.x & 63;
    int i = blockIdx.x * 4 + wv;
    if (i >= N) return;
    int l5 = lane & 31;
    int half = lane >> 5;
    int start = rp[i], end = rp[i + 1];
    int deg = end - start;
    uint2* o2 = (uint2*)agg;
    if (deg == 0) {
        // keep old h: decode self fp8 row to bf16 (exact for the zeroed deg col: true deg = 0)
        if (half == 0) {
            unsigned v = h8[(size_t)i * 32 + l5];
            floatx2 lo = __builtin_amdgcn_cvt_pk_f32_fp8(v, false);
            floatx2 hi = __builtin_amdgcn_cvt_pk_f32_fp8(v, true);
            uint2 r;
            r.x = pack_bf2(lo[0], lo[1]);
            r.y = pack_bf2(hi[0], hi[1]);
            o2[(size_t)i * 32 + l5] = r;
        }
        return;
    }
    float a0 = 0.f, a1 = 0.f, a2 = 0.f, a3 = 0.f;
    float dsum = 0.f;
    int e = start;
    while (e < end) {
        int rem = end - e;
        if (rem >= 16) {
            int idx = csr[e + (lane & 15)];
            if (degf) dsum += degf[idx];
            int woff[8];
            unsigned v[8];
            #pragma unroll
            for (int p = 0; p < 8; ++p) {
                int s0 = __builtin_amdgcn_readlane(idx, 2 * p);
                int s1 = __builtin_amdgcn_readlane(idx, 2 * p + 1);
                woff[p] = (half ? s1 : s0) * 32 + l5;
            }
            #pragma unroll
            for (int p = 0; p < 8; ++p) v[p] = h8[woff[p]];
            #pragma unroll
            for (int p = 0; p < 8; ++p) {
                floatx2 lo = __builtin_amdgcn_cvt_pk_f32_fp8(v[p], false);
                floatx2 hi = __builtin_amdgcn_cvt_pk_f32_fp8(v[p], true);
                a0 += lo[0]; a1 += lo[1]; a2 += hi[0]; a3 += hi[1];
            }
            e += 16;
        } else {
            int idx = csr[e + min(lane & 15, rem - 1)];
            if (degf && (lane & 15) < rem) dsum += degf[idx];
            #pragma unroll
            for (int p = 0; p < 8; ++p) {
                if (2 * p >= rem) break;
                int k1 = min(2 * p + 1, rem - 1);
                int s0 = __builtin_amdgcn_readlane(idx, 2 * p);
                int s1 = __builtin_amdgcn_readlane(idx, k1);
                unsigned v = h8[(half ? s1 : s0) * 32 + l5];
                if (2 * p + 1 >= rem && half) v = 0u;   // odd tail: upper half-row invalid
                floatx2 lo = __builtin_amdgcn_cvt_pk_f32_fp8(v, false);
                floatx2 hi = __builtin_amdgcn_cvt_pk_f32_fp8(v, true);
                a0 += lo[0]; a1 += lo[1]; a2 += hi[0]; a3 += hi[1];
            }
            e = end;
        }
    }
    if (degf) {
        // full-wave reduce of dsum (each neighbor's deg counted 4x)
        #pragma unroll
        for (int off = 1; off < 64; off <<= 1) dsum += __shfl_xor(dsum, off);
        if (l5 == 0 && half == 0) a0 = dsum * 0.25f;   // exact neighbor-deg sum -> col0
    }
    a0 += __shfl_xor(a0, 32);
    a1 += __shfl_xor(a1, 32);
    a2 += __shfl_xor(a2, 32);
    a3 += __shfl_xor(a3, 32);
    if (half == 0) {
        float inv = 1.f / (float)deg;
        uint2 r;
        r.x = pack_bf2(a0 * inv, a1 * inv);
        r.y = pack_bf2(a2 * inv, a3 * inv);
        o2[(size_t)i * 32 + l5] = r;
    }
}

// ---------------- GEMM: relu(A @ W^T + b) via MFMA bf16; out fp8 and/or bf16 ----------------
// A [N,128] bf16, Wb [128,128] bf16. 16x16x32 layouts: A/B lane = [idx=lane&15][k=(lane>>4)*8+j];
// C/D: col = lane&15, row = (lane>>4)*4 + reg.

__global__ __launch_bounds__(256) void mfma_gemm_kernel(const unsigned* __restrict__ A,
                                                        unsigned* __restrict__ out8,
                                                        unsigned* __restrict__ outb,
                                                        const unsigned* __restrict__ Wb,
                                                        const float* __restrict__ bias, int N) {
    __shared__ unsigned Al[64 * APAD];
    int t = threadIdx.x;
    int n0 = blockIdx.x * 64;
    #pragma unroll
    for (int c = 0; c < 4; ++c) {
        int f = c * 256 + t;
        int row = f >> 4, c4 = f & 15;
        int n = n0 + row;
        uint4 v = make_uint4(0u, 0u, 0u, 0u);
        if (n < N) v = ((const uint4*)A)[(size_t)n * 16 + c4];
        *(uint4*)&Al[row * APAD + c4 * 4] = v;
    }
    __syncthreads();

    int wv = t >> 6, lane = t & 63;
    int m = lane & 15, q = lane >> 4;
    floatx4 acc[8];
    #pragma unroll
    for (int ot = 0; ot < 8; ++ot) acc[ot] = (floatx4)(0.f);

    #pragma unroll
    for (int kt = 0; kt < 4; ++kt) {
        short8 af = *(const short8*)&Al[(wv * 16 + m) * APAD + kt * 16 + q * 4];
        short8 bf[8];
        #pragma unroll
        for (int ot = 0; ot < 8; ++ot)
            bf[ot] = *(const short8*)&Wb[(ot * 16 + m) * 64 + kt * 16 + q * 4];
        #pragma unroll
        for (int ot = 0; ot < 8; ++ot)
            acc[ot] = __builtin_amdgcn_mfma_f32_16x16x32_bf16(af, bf[ot], acc[ot], 0, 0, 0);
    }

    unsigned short* oh = (unsigned short*)outb;
    unsigned char* o8 = (unsigned char*)out8;
    #pragma unroll
    for (int ot = 0; ot < 8; ++ot) {
        int o = ot * 16 + m;
        float bv = bias[o];
        #pragma unroll
        for (int r = 0; r < 4; ++r) {
            int n = n0 + wv * 16 + q * 4 + r;
            if (n < N) {
                float v = fmaxf(acc[ot][r] + bv, 0.f);
                if (outb) {
                    unsigned bx = __float_as_uint(v);
                    bx += 0x7fffu + ((bx >> 16) & 1u);
                    oh[(size_t)n * 128 + o] = (unsigned short)(bx >> 16);
                }
                if (out8) {
                    unsigned pk = __builtin_amdgcn_cvt_pk_fp8_f32(v, v, 0, false);
                    o8[(size_t)n * 128 + o] = (unsigned char)(pk & 0xffu);
                }
            }
        }
    }
}

// ---------------- graph mean-pool + counts (merged) ----------------

__global__ void pool_kernel(const unsigned* __restrict__ h, const int* __restrict__ gid,
                            float* __restrict__ hg, float* __restrict__ counts, int N) {
    int c = threadIdx.x & 63;
    int half = threadIdx.x >> 6;
    int n0 = blockIdx.x * 512;
    int nend = min(n0 + 512, N);
    float ax = 0.f, ay = 0.f, cnt = 0.f;
    int cur = -1;
    for (int n = n0 + half; n < nend; n += 4) {
        int g = gid[n];
        if (g != cur) {
            if (cur >= 0) {
                atomicAdd(&hg[cur * HID + 2 * c], ax);
                atomicAdd(&hg[cur * HID + 2 * c + 1], ay);
                if (c == 0) atomicAdd(&counts[cur], cnt);
            }
            ax = ay = cnt = 0.f;
            cur = g;
        }
        unsigned v = h[(size_t)n * 64 + c];
        ax += bf_lo(v); ay += bf_hi(v);
        cnt += 1.f;
    }
    if (cur >= 0) {
        atomicAdd(&hg[cur * HID + 2 * c], ax);
        atomicAdd(&hg[cur * HID + 2 * c + 1], ay);
        if (c == 0) atomicAdd(&counts[cur], cnt);
    }
}

// ---------------- fused classifier head (fp32), one block per graph ----------------

__global__ __launch_bounds__(128) void cls_fused_kernel(const float* __restrict__ hg,
                                                        const float* __restrict__ counts,
                                                        const float* __restrict__ Wc1,
                                                        const float* __restrict__ bc1,
                                                        const float* __restrict__ Wc2,
                                                        const float* __restrict__ bc2,
                                                        float* __restrict__ out, int G) {
    __shared__ float x[128];
    __shared__ float y[128];
    __shared__ float red[128];
    int g = blockIdx.x, t = threadIdx.x;
    float inv = 1.f / fmaxf(counts[g], 1.f);
    x[t] = hg[g * HID + t] * inv;
    __syncthreads();
    const float4* w4 = (const float4*)(Wc1 + t * HID);
    float s = 0.f;
    #pragma unroll
    for (int k4 = 0; k4 < 32; ++k4) {
        float4 w = w4[k4];
        s += x[k4 * 4] * w.x + x[k4 * 4 + 1] * w.y + x[k4 * 4 + 2] * w.z + x[k4 * 4 + 3] * w.w;
    }
    y[t] = s + bc1[t];
    __syncthreads();
    float s2 = 0.f;
    #pragma unroll
    for (int k4 = 0; k4 < 32; ++k4) {
        float4 w = w4[k4];
        s2 += y[k4 * 4] * w.x + y[k4 * 4 + 1] * w.y + y[k4 * 4 + 2] * w.z + y[k4 * 4 + 3] * w.w;
    }
    red[t] = (s2 + bc1[t]) * Wc2[t];
    __syncthreads();
    if (t < 64) {
        float r = red[t] + red[t + 64];
        #pragma unroll
        for (int off = 32; off > 0; off >>= 1) r += __shfl_down(r, off);
        if (t == 0) out[g] = r + bc2[0];
    }
}

// ---------------- launch ----------------

extern "C" void kernel_launch(void* const* d_in, const int* in_sizes, int n_in,
                              void* d_out, int out_size, void* d_ws, size_t ws_size,
                              hipStream_t stream) {
    const float* feat = (const float*)d_in[0];
    const int* src    = (const int*)d_in[1];
    const int* dst    = (const int*)d_in[2];
    const int* gid    = (const int*)d_in[3];
    const float* W0  = (const float*)d_in[5];
    const float* b0  = (const float*)d_in[6];
    const float* W1  = (const float*)d_in[7];
    const float* b1  = (const float*)d_in[8];
    const float* W2  = (const float*)d_in[9];
    const float* b2  = (const float*)d_in[10];
    const float* Wc1 = (const float*)d_in[11];
    const float* bc1 = (const float*)d_in[12];
    const float* Wc2 = (const float*)d_in[13];
    const float* bc2 = (const float*)d_in[14];

    const int N = in_sizes[3];
    const int E = in_sizes[1];
    const int G = out_size;
    const int NB = (N + BNODES - 1) >> BSH;

    char* ws = (char*)d_ws;
    size_t off = 0;
    auto alloc = [&](size_t bytes) { void* p = ws + off; off += (bytes + 255) & ~size_t(255); return p; };
    unsigned* h8     = (unsigned*)alloc((size_t)N * 32 * 4);   // fp8 h (h0 -> h1 -> h2, reused)
    unsigned* hB     = (unsigned*)alloc((size_t)N * 64 * 4);   // bf16 h3 for pool
    unsigned* aggbuf = (unsigned*)alloc((size_t)N * 64 * 4);   // bf16 GEMM input
    float* degf      = (float*)alloc((size_t)N * 4);
    uint2* staging   = (uint2*)alloc((size_t)E * 8);
    int* csr         = (int*)alloc((size_t)E * 4);
    int* rp          = (int*)alloc((size_t)(N + 1) * 4);
    int* gbucket     = (int*)alloc(512 * 4);
    int* bstart      = (int*)alloc(513 * 4);
    int* gcur        = (int*)alloc(512 * 4);
    unsigned* Wb0    = (unsigned*)alloc(8192 * 4);
    unsigned* Wb1    = (unsigned*)alloc(8192 * 4);
    unsigned* Wb2    = (unsigned*)alloc(8192 * 4);
    float* hg        = (float*)alloc((size_t)G * HID * 4);
    float* counts    = (float*)alloc((size_t)G * 4);

    init_kernel<<<96, 256, 0, stream>>>(W0, W1, W2, Wb0, Wb1, Wb2, gbucket, hg, counts, G);

    int gE = (E + 4095) / 4096;
    bucket_count_kernel<<<gE, 256, 0, stream>>>(dst, gbucket, E, NB);
    bucket_scan_kernel<<<1, 512, 0, stream>>>(gbucket, bstart, gcur, NB, E);
    bucket_scatter_kernel<<<gE, 256, 0, stream>>>(src, dst, gcur, staging, E, NB);
    csr_build_kernel<<<NB, 256, 0, stream>>>(staging, bstart, rp, csr, N, E, NB);

    build_h0_kernel<<<(N * 32 + 255) / 256, 256, 0, stream>>>(feat, rp, h8, degf, N);

    int agg_grid = (N + 3) / 4;
    int gemm_grid = (N + 63) / 64;

    agg_fp8_kernel<<<agg_grid, 256, 0, stream>>>(h8, aggbuf, rp, csr, degf, N);
    mfma_gemm_kernel<<<gemm_grid, 256, 0, stream>>>(aggbuf, h8, nullptr, Wb0, b0, N);

    agg_fp8_kernel<<<agg_grid, 256, 0, stream>>>(h8, aggbuf, rp, csr, nullptr, N);
    mfma_gemm_kernel<<<gemm_grid, 256, 0, stream>>>(aggbuf, h8, nullptr, Wb1, b1, N);

    agg_fp8_kernel<<<agg_grid, 256, 0, stream>>>(h8, aggbuf, rp, csr, nullptr, N);
    mfma_gemm_kernel<<<gemm_grid, 256, 0, stream>>>(aggbuf, nullptr, hB, Wb2, b2, N);

    pool_kernel<<<(N + 511) / 512, 256, 0, stream>>>(hB, gid, hg, counts, N);

    cls_fused_kernel<<<G, 128, 0, stream>>>(hg, counts, Wc1, bc1, Wc2, bc2, (float*)d_out, G);
}

// Round 6
// 477.178 us; speedup vs baseline: 1.4986x; 1.0669x over previous
//
#include <hip/hip_runtime.h>
#include <hip/hip_bf16.h>

#define HID 128
#define NRAW 127
#define BSH 8          // 256 nodes per bucket
#define BNODES 256
#define APAD 68        // LDS row pitch in u32 (16B-aligned, breaks pow2 stride)

typedef __attribute__((ext_vector_type(8))) short short8;
typedef __attribute__((ext_vector_type(4))) float floatx4;
typedef __attribute__((ext_vector_type(2))) float floatx2;

__device__ inline unsigned pack_bf2(float x, float y) {
    unsigned bx = __float_as_uint(x);
    unsigned by = __float_as_uint(y);
    bx += 0x7fffu + ((bx >> 16) & 1u);   // RNE
    by += 0x7fffu + ((by >> 16) & 1u);
    return (bx >> 16) | (by & 0xffff0000u);
}
__device__ inline float bf_lo(unsigned u) { return __uint_as_float(u << 16); }
__device__ inline float bf_hi(unsigned u) { return __uint_as_float(u & 0xffff0000u); }

// ---------------- init: zeros + weight bf16 pack ----------------

__global__ void init_kernel(const float* __restrict__ W0, const float* __restrict__ W1,
                            const float* __restrict__ W2,
                            unsigned* __restrict__ O0, unsigned* __restrict__ O1,
                            unsigned* __restrict__ O2,
                            int* __restrict__ gbucket, float* __restrict__ hg,
                            float* __restrict__ counts, int G) {
    int id = blockIdx.x * blockDim.x + threadIdx.x;
    if (id < 512) gbucket[id] = 0;
    if (id < G * HID) hg[id] = 0.f;
    if (id < G) counts[id] = 0.f;
    if (id < 3 * 8192) {
        int sel = id >> 13, l = id & 8191;
        const float* W = sel == 0 ? W0 : (sel == 1 ? W1 : W2);
        unsigned* O = sel == 0 ? O0 : (sel == 1 ? O1 : O2);
        O[l] = pack_bf2(W[2 * l], W[2 * l + 1]);
    }
}

// ---------------- CSR build: bucketed 2-phase counting sort ----------------

__global__ __launch_bounds__(256) void bucket_count_kernel(const int* __restrict__ dst,
                                                           int* __restrict__ gbucket,
                                                           int E, int NB) {
    __shared__ int hist[512];
    int t = threadIdx.x;
    for (int b = t; b < NB; b += 256) hist[b] = 0;
    __syncthreads();
    int base = blockIdx.x * 4096;
    #pragma unroll
    for (int j = 0; j < 16; ++j) {
        int e = base + j * 256 + t;
        if (e < E) atomicAdd(&hist[dst[e] >> BSH], 1);
    }
    __syncthreads();
    for (int b = t; b < NB; b += 256) {
        int v = hist[b];
        if (v) atomicAdd(&gbucket[b], v);
    }
}

__global__ void bucket_scan_kernel(const int* __restrict__ gbucket, int* __restrict__ bstart,
                                   int* __restrict__ gcur, int NB, int E) {
    __shared__ int sm[512];
    int t = threadIdx.x;
    int v = (t < NB) ? gbucket[t] : 0;
    sm[t] = v;
    __syncthreads();
    for (int off = 1; off < 512; off <<= 1) {
        int add = (t >= off) ? sm[t - off] : 0;
        __syncthreads();
        sm[t] += add;
        __syncthreads();
    }
    if (t < NB) {
        int ex = sm[t] - v;
        bstart[t] = ex;
        gcur[t] = ex;
    }
    if (t == 0) bstart[NB] = E;
}

__global__ __launch_bounds__(256) void bucket_scatter_kernel(const int* __restrict__ src,
                                                             const int* __restrict__ dst,
                                                             int* __restrict__ gcur,
                                                             uint2* __restrict__ staging,
                                                             int E, int NB) {
    __shared__ int hist[512];
    __shared__ int base[512];
    int t = threadIdx.x;
    for (int b = t; b < NB; b += 256) hist[b] = 0;
    __syncthreads();
    int s[16], d[16], r[16];
    int e0 = blockIdx.x * 4096;
    #pragma unroll
    for (int j = 0; j < 16; ++j) {
        int e = e0 + j * 256 + t;
        if (e < E) {
            s[j] = src[e];
            d[j] = dst[e];
            r[j] = atomicAdd(&hist[d[j] >> BSH], 1);
        } else d[j] = -1;
    }
    __syncthreads();
    for (int b = t; b < NB; b += 256) {
        int v = hist[b];
        base[b] = v ? atomicAdd(&gcur[b], v) : 0;
    }
    __syncthreads();
    #pragma unroll
    for (int j = 0; j < 16; ++j) {
        if (d[j] >= 0) {
            int b = d[j] >> BSH;
            staging[base[b] + r[j]] = make_uint2((unsigned)s[j], (unsigned)d[j]);
        }
    }
}

__global__ __launch_bounds__(256) void csr_build_kernel(const uint2* __restrict__ staging,
                                                        const int* __restrict__ bstart,
                                                        int* __restrict__ rp, int* __restrict__ csr,
                                                        int N, int E, int NB) {
    __shared__ int hist[256];
    __shared__ int sm[256];
    __shared__ int excl[256];
    __shared__ int cnt[256];
    int t = threadIdx.x;
    int b = blockIdx.x;
    int nbase = b << BSH;
    int s0 = bstart[b], e1 = bstart[b + 1];
    hist[t] = 0;
    __syncthreads();
    for (int i = s0 + t; i < e1; i += 256) {
        uint2 p = staging[i];
        atomicAdd(&hist[p.y & (BNODES - 1)], 1);
    }
    __syncthreads();
    int h = hist[t];
    sm[t] = h;
    __syncthreads();
    for (int off = 1; off < 256; off <<= 1) {
        int add = (t >= off) ? sm[t - off] : 0;
        __syncthreads();
        sm[t] += add;
        __syncthreads();
    }
    excl[t] = sm[t] - h;
    cnt[t] = 0;
    int n = nbase + t;
    if (n < N) rp[n] = s0 + (sm[t] - h);
    if (b == NB - 1 && t == 0) rp[N] = E;
    __syncthreads();
    for (int i = s0 + t; i < e1; i += 256) {
        uint2 p = staging[i];
        int dl = p.y & (BNODES - 1);
        int pos = s0 + excl[dl] + atomicAdd(&cnt[dl], 1);
        csr[pos] = (int)p.x;
    }
}

// ---------------- h0 in fp8 (col0 zeroed) + exact degf ----------------

__global__ void build_h0_kernel(const float* __restrict__ feat, const int* __restrict__ rp,
                                unsigned* __restrict__ h8, float* __restrict__ degf, int N) {
    int id = blockIdx.x * blockDim.x + threadIdx.x;
    if (id >= N * 32) return;
    int n = id >> 5, c = id & 31;
    const float* fr = feat + (size_t)n * NRAW;
    float f0, f1, f2, f3;
    if (c == 0) {
        f0 = 0.f;          // deg column handled exactly via degf in layer-0 agg
        f1 = fr[0]; f2 = fr[1]; f3 = fr[2];
    } else {
        int b = 4 * c - 1;
        f0 = fr[b]; f1 = fr[b + 1]; f2 = fr[b + 2]; f3 = fr[b + 3];
    }
    unsigned w = __builtin_amdgcn_cvt_pk_fp8_f32(f0, f1, 0, false);
    w = __builtin_amdgcn_cvt_pk_fp8_f32(f2, f3, w, true);
    h8[id] = w;
    if (c == 0) degf[n] = (float)(rp[n + 1] - rp[n]);
}

// ---------------- aggregation: fp8 gather, one wave per node, 4 rows per wave-load ----------------
// h8 [N][16] uint2 (=128 fp8 cols, 128 B/row). Lane layout: grp = lane>>4 selects one of 4
// neighbor rows per load; col = lane&15 selects uint2 within row. Accumulate in packed floatx2.
// out bf16 [N][64] u32. If degf != null (layer 0), col0 of the mean is exact from degf.

__global__ __launch_bounds__(256) void agg_fp8_kernel(const unsigned* __restrict__ h8,
                                                      unsigned* __restrict__ agg,
                                                      const int* __restrict__ rp,
                                                      const int* __restrict__ csr,
                                                      const float* __restrict__ degf, int N) {
    int wv = threadIdx.x >> 6, lane = threadIdx.x & 63;
    int i = blockIdx.x * 4 + wv;
    if (i >= N) return;
    int grp = lane >> 4;
    int col = lane & 15;
    int start = rp[i], end = rp[i + 1];
    int deg = end - start;
    const uint2* h2 = (const uint2*)h8;
    if (deg == 0) {
        // keep old h: decode self fp8 row to bf16 (exact for zeroed deg col: true deg = 0)
        if (grp == 0) {
            uint2 v = h2[(size_t)i * 16 + col];
            floatx2 l0 = __builtin_amdgcn_cvt_pk_f32_fp8(v.x, false);
            floatx2 h0 = __builtin_amdgcn_cvt_pk_f32_fp8(v.x, true);
            floatx2 l1 = __builtin_amdgcn_cvt_pk_f32_fp8(v.y, false);
            floatx2 h1 = __builtin_amdgcn_cvt_pk_f32_fp8(v.y, true);
            uint4 r;
            r.x = pack_bf2(l0[0], l0[1]);
            r.y = pack_bf2(h0[0], h0[1]);
            r.z = pack_bf2(l1[0], l1[1]);
            r.w = pack_bf2(h1[0], h1[1]);
            ((uint4*)agg)[(size_t)i * 16 + col] = r;
        }
        return;
    }
    floatx2 a0 = {0.f, 0.f}, a1 = {0.f, 0.f}, a2 = {0.f, 0.f}, a3 = {0.f, 0.f};
    float dsum = 0.f;
    for (int e = start; e < end; e += 64) {
        int nb = min(end - e, 64);
        int myidx = csr[e + min(lane, nb - 1)];
        if (degf && lane < nb) dsum += degf[myidx];
        int e2 = 0;
        while (e2 + 16 <= nb) {
            int ridx[4];
            uint2 v[4];
            #pragma unroll
            for (int j = 0; j < 4; ++j) ridx[j] = __shfl(myidx, e2 + 4 * j + grp);
            #pragma unroll
            for (int j = 0; j < 4; ++j) v[j] = h2[(size_t)ridx[j] * 16 + col];
            #pragma unroll
            for (int j = 0; j < 4; ++j) {
                a0 += __builtin_amdgcn_cvt_pk_f32_fp8(v[j].x, false);
                a1 += __builtin_amdgcn_cvt_pk_f32_fp8(v[j].x, true);
                a2 += __builtin_amdgcn_cvt_pk_f32_fp8(v[j].y, false);
                a3 += __builtin_amdgcn_cvt_pk_f32_fp8(v[j].y, true);
            }
            e2 += 16;
        }
        int tb = nb - e2;
        if (tb) {
            int ridx[4];
            uint2 v[4];
            #pragma unroll
            for (int j = 0; j < 4; ++j) ridx[j] = __shfl(myidx, e2 + min(4 * j + grp, tb - 1));
            #pragma unroll
            for (int j = 0; j < 4; ++j)
                v[j] = (4 * j < tb) ? h2[(size_t)ridx[j] * 16 + col] : make_uint2(0u, 0u);
            #pragma unroll
            for (int j = 0; j < 4; ++j) {
                uint2 vv = v[j];
                if (4 * j + grp >= tb) { vv.x = 0u; vv.y = 0u; }   // fp8 0x00 == 0.0
                a0 += __builtin_amdgcn_cvt_pk_f32_fp8(vv.x, false);
                a1 += __builtin_amdgcn_cvt_pk_f32_fp8(vv.x, true);
                a2 += __builtin_amdgcn_cvt_pk_f32_fp8(vv.y, false);
                a3 += __builtin_amdgcn_cvt_pk_f32_fp8(vv.y, true);
            }
        }
    }
    // cross-group reduce: lanes l, l^16, l^32, l^48 hold same columns
    #pragma unroll
    for (int s = 16; s <= 32; s <<= 1) {
        a0[0] += __shfl_xor(a0[0], s); a0[1] += __shfl_xor(a0[1], s);
        a1[0] += __shfl_xor(a1[0], s); a1[1] += __shfl_xor(a1[1], s);
        a2[0] += __shfl_xor(a2[0], s); a2[1] += __shfl_xor(a2[1], s);
        a3[0] += __shfl_xor(a3[0], s); a3[1] += __shfl_xor(a3[1], s);
    }
    if (degf) {
        #pragma unroll
        for (int s = 1; s < 64; s <<= 1) dsum += __shfl_xor(dsum, s);
        if (lane == 0) a0[0] = dsum;   // exact neighbor-deg sum -> col0
    }
    if (grp == 0) {
        float inv = 1.f / (float)deg;
        uint4 r;
        r.x = pack_bf2(a0[0] * inv, a0[1] * inv);
        r.y = pack_bf2(a1[0] * inv, a1[1] * inv);
        r.z = pack_bf2(a2[0] * inv, a2[1] * inv);
        r.w = pack_bf2(a3[0] * inv, a3[1] * inv);
        ((uint4*)agg)[(size_t)i * 16 + col] = r;
    }
}

// ---------------- GEMM: relu(A @ W^T + b) via MFMA bf16; out fp8 and/or bf16 ----------------
// A [N,128] bf16, Wb [128,128] bf16. 16x16x32 layouts: A/B lane = [idx=lane&15][k=(lane>>4)*8+j];
// C/D: col = lane&15, row = (lane>>4)*4 + reg.

__global__ __launch_bounds__(256) void mfma_gemm_kernel(const unsigned* __restrict__ A,
                                                        unsigned* __restrict__ out8,
                                                        unsigned* __restrict__ outb,
                                                        const unsigned* __restrict__ Wb,
                                                        const float* __restrict__ bias, int N) {
    __shared__ unsigned Al[64 * APAD];
    int t = threadIdx.x;
    int n0 = blockIdx.x * 64;
    #pragma unroll
    for (int c = 0; c < 4; ++c) {
        int f = c * 256 + t;
        int row = f >> 4, c4 = f & 15;
        int n = n0 + row;
        uint4 v = make_uint4(0u, 0u, 0u, 0u);
        if (n < N) v = ((const uint4*)A)[(size_t)n * 16 + c4];
        *(uint4*)&Al[row * APAD + c4 * 4] = v;
    }
    __syncthreads();

    int wv = t >> 6, lane = t & 63;
    int m = lane & 15, q = lane >> 4;
    floatx4 acc[8];
    #pragma unroll
    for (int ot = 0; ot < 8; ++ot) acc[ot] = (floatx4)(0.f);

    #pragma unroll
    for (int kt = 0; kt < 4; ++kt) {
        short8 af = *(const short8*)&Al[(wv * 16 + m) * APAD + kt * 16 + q * 4];
        short8 bf[8];
        #pragma unroll
        for (int ot = 0; ot < 8; ++ot)
            bf[ot] = *(const short8*)&Wb[(ot * 16 + m) * 64 + kt * 16 + q * 4];
        #pragma unroll
        for (int ot = 0; ot < 8; ++ot)
            acc[ot] = __builtin_amdgcn_mfma_f32_16x16x32_bf16(af, bf[ot], acc[ot], 0, 0, 0);
    }

    unsigned short* oh = (unsigned short*)outb;
    unsigned char* o8 = (unsigned char*)out8;
    #pragma unroll
    for (int ot = 0; ot < 8; ++ot) {
        int o = ot * 16 + m;
        float bv = bias[o];
        #pragma unroll
        for (int r = 0; r < 4; ++r) {
            int n = n0 + wv * 16 + q * 4 + r;
            if (n < N) {
                float v = fmaxf(acc[ot][r] + bv, 0.f);
                if (outb) {
                    unsigned bx = __float_as_uint(v);
                    bx += 0x7fffu + ((bx >> 16) & 1u);
                    oh[(size_t)n * 128 + o] = (unsigned short)(bx >> 16);
                }
                if (out8) {
                    unsigned pk = __builtin_amdgcn_cvt_pk_fp8_f32(v, v, 0, false);
                    o8[(size_t)n * 128 + o] = (unsigned char)(pk & 0xffu);
                }
            }
        }
    }
}

// ---------------- graph mean-pool + counts (merged) ----------------

__global__ void pool_kernel(const unsigned* __restrict__ h, const int* __restrict__ gid,
                            float* __restrict__ hg, float* __restrict__ counts, int N) {
    int c = threadIdx.x & 63;
    int half = threadIdx.x >> 6;
    int n0 = blockIdx.x * 512;
    int nend = min(n0 + 512, N);
    float ax = 0.f, ay = 0.f, cnt = 0.f;
    int cur = -1;
    for (int n = n0 + half; n < nend; n += 4) {
        int g = gid[n];
        if (g != cur) {
            if (cur >= 0) {
                atomicAdd(&hg[cur * HID + 2 * c], ax);
                atomicAdd(&hg[cur * HID + 2 * c + 1], ay);
                if (c == 0) atomicAdd(&counts[cur], cnt);
            }
            ax = ay = cnt = 0.f;
            cur = g;
        }
        unsigned v = h[(size_t)n * 64 + c];
        ax += bf_lo(v); ay += bf_hi(v);
        cnt += 1.f;
    }
    if (cur >= 0) {
        atomicAdd(&hg[cur * HID + 2 * c], ax);
        atomicAdd(&hg[cur * HID + 2 * c + 1], ay);
        if (c == 0) atomicAdd(&counts[cur], cnt);
    }
}

// ---------------- fused classifier head (fp32), one block per graph ----------------

__global__ __launch_bounds__(128) void cls_fused_kernel(const float* __restrict__ hg,
                                                        const float* __restrict__ counts,
                                                        const float* __restrict__ Wc1,
                                                        const float* __restrict__ bc1,
                                                        const float* __restrict__ Wc2,
                                                        const float* __restrict__ bc2,
                                                        float* __restrict__ out, int G) {
    __shared__ float x[128];
    __shared__ float y[128];
    __shared__ float red[128];
    int g = blockIdx.x, t = threadIdx.x;
    float inv = 1.f / fmaxf(counts[g], 1.f);
    x[t] = hg[g * HID + t] * inv;
    __syncthreads();
    const float4* w4 = (const float4*)(Wc1 + t * HID);
    float s = 0.f;
    #pragma unroll
    for (int k4 = 0; k4 < 32; ++k4) {
        float4 w = w4[k4];
        s += x[k4 * 4] * w.x + x[k4 * 4 + 1] * w.y + x[k4 * 4 + 2] * w.z + x[k4 * 4 + 3] * w.w;
    }
    y[t] = s + bc1[t];
    __syncthreads();
    float s2 = 0.f;
    #pragma unroll
    for (int k4 = 0; k4 < 32; ++k4) {
        float4 w = w4[k4];
        s2 += y[k4 * 4] * w.x + y[k4 * 4 + 1] * w.y + y[k4 * 4 + 2] * w.z + y[k4 * 4 + 3] * w.w;
    }
    red[t] = (s2 + bc1[t]) * Wc2[t];
    __syncthreads();
    if (t < 64) {
        float r = red[t] + red[t + 64];
        #pragma unroll
        for (int off = 32; off > 0; off >>= 1) r += __shfl_down(r, off);
        if (t == 0) out[g] = r + bc2[0];
    }
}

// ---------------- launch ----------------

extern "C" void kernel_launch(void* const* d_in, const int* in_sizes, int n_in,
                              void* d_out, int out_size, void* d_ws, size_t ws_size,
                              hipStream_t stream) {
    const float* feat = (const float*)d_in[0];
    const int* src    = (const int*)d_in[1];
    const int* dst    = (const int*)d_in[2];
    const int* gid    = (const int*)d_in[3];
    const float* W0  = (const float*)d_in[5];
    const float* b0  = (const float*)d_in[6];
    const float* W1  = (const float*)d_in[7];
    const float* b1  = (const float*)d_in[8];
    const float* W2  = (const float*)d_in[9];
    const float* b2  = (const float*)d_in[10];
    const float* Wc1 = (const float*)d_in[11];
    const float* bc1 = (const float*)d_in[12];
    const float* Wc2 = (const float*)d_in[13];
    const float* bc2 = (const float*)d_in[14];

    const int N = in_sizes[3];
    const int E = in_sizes[1];
    const int G = out_size;
    const int NB = (N + BNODES - 1) >> BSH;

    char* ws = (char*)d_ws;
    size_t off = 0;
    auto alloc = [&](size_t bytes) { void* p = ws + off; off += (bytes + 255) & ~size_t(255); return p; };
    unsigned* h8     = (unsigned*)alloc((size_t)N * 32 * 4);   // fp8 h (h0 -> h1 -> h2, reused)
    unsigned* hB     = (unsigned*)alloc((size_t)N * 64 * 4);   // bf16 h3 for pool
    unsigned* aggbuf = (unsigned*)alloc((size_t)N * 64 * 4);   // bf16 GEMM input
    float* degf      = (float*)alloc((size_t)N * 4);
    uint2* staging   = (uint2*)alloc((size_t)E * 8);
    int* csr         = (int*)alloc((size_t)E * 4);
    int* rp          = (int*)alloc((size_t)(N + 1) * 4);
    int* gbucket     = (int*)alloc(512 * 4);
    int* bstart      = (int*)alloc(513 * 4);
    int* gcur        = (int*)alloc(512 * 4);
    unsigned* Wb0    = (unsigned*)alloc(8192 * 4);
    unsigned* Wb1    = (unsigned*)alloc(8192 * 4);
    unsigned* Wb2    = (unsigned*)alloc(8192 * 4);
    float* hg        = (float*)alloc((size_t)G * HID * 4);
    float* counts    = (float*)alloc((size_t)G * 4);

    init_kernel<<<96, 256, 0, stream>>>(W0, W1, W2, Wb0, Wb1, Wb2, gbucket, hg, counts, G);

    int gE = (E + 4095) / 4096;
    bucket_count_kernel<<<gE, 256, 0, stream>>>(dst, gbucket, E, NB);
    bucket_scan_kernel<<<1, 512, 0, stream>>>(gbucket, bstart, gcur, NB, E);
    bucket_scatter_kernel<<<gE, 256, 0, stream>>>(src, dst, gcur, staging, E, NB);
    csr_build_kernel<<<NB, 256, 0, stream>>>(staging, bstart, rp, csr, N, E, NB);

    build_h0_kernel<<<(N * 32 + 255) / 256, 256, 0, stream>>>(feat, rp, h8, degf, N);

    int agg_grid = (N + 3) / 4;
    int gemm_grid = (N + 63) / 64;

    agg_fp8_kernel<<<agg_grid, 256, 0, stream>>>(h8, aggbuf, rp, csr, degf, N);
    mfma_gemm_kernel<<<gemm_grid, 256, 0, stream>>>(aggbuf, h8, nullptr, Wb0, b0, N);

    agg_fp8_kernel<<<agg_grid, 256, 0, stream>>>(h8, aggbuf, rp, csr, nullptr, N);
    mfma_gemm_kernel<<<gemm_grid, 256, 0, stream>>>(aggbuf, h8, nullptr, Wb1, b1, N);

    agg_fp8_kernel<<<agg_grid, 256, 0, stream>>>(h8, aggbuf, rp, csr, nullptr, N);
    mfma_gemm_kernel<<<gemm_grid, 256, 0, stream>>>(aggbuf, nullptr, hB, Wb2, b2, N);

    pool_kernel<<<(N + 511) / 512, 256, 0, stream>>>(hB, gid, hg, counts, N);

    cls_fused_kernel<<<G, 128, 0, stream>>>(hg, counts, Wc1, bc1, Wc2, bc2, (float*)d_out, G);
}

// Round 7
// 472.672 us; speedup vs baseline: 1.5129x; 1.0095x over previous
//
#include <hip/hip_runtime.h>
#include <hip/hip_bf16.h>

#define HID 128
#define NRAW 127
#define BSH 8          // 256 nodes per bucket
#define BNODES 256
#define APAD 68        // LDS row pitch in u32 (16B-aligned, breaks pow2 stride)

typedef __attribute__((ext_vector_type(8))) short short8;
typedef __attribute__((ext_vector_type(4))) float floatx4;
typedef __attribute__((ext_vector_type(2))) float floatx2;

__device__ inline unsigned pack_bf2(float x, float y) {
    unsigned bx = __float_as_uint(x);
    unsigned by = __float_as_uint(y);
    bx += 0x7fffu + ((bx >> 16) & 1u);   // RNE
    by += 0x7fffu + ((by >> 16) & 1u);
    return (bx >> 16) | (by & 0xffff0000u);
}
__device__ inline float bf_lo(unsigned u) { return __uint_as_float(u << 16); }
__device__ inline float bf_hi(unsigned u) { return __uint_as_float(u & 0xffff0000u); }

// ---------------- init: zeros + weight bf16 pack ----------------

__global__ void init_kernel(const float* __restrict__ W0, const float* __restrict__ W1,
                            const float* __restrict__ W2,
                            unsigned* __restrict__ O0, unsigned* __restrict__ O1,
                            unsigned* __restrict__ O2,
                            int* __restrict__ gbucket, float* __restrict__ hg,
                            float* __restrict__ counts, int G) {
    int id = blockIdx.x * blockDim.x + threadIdx.x;
    if (id < 512) gbucket[id] = 0;
    if (id < G * HID) hg[id] = 0.f;
    if (id < G) counts[id] = 0.f;
    if (id < 3 * 8192) {
        int sel = id >> 13, l = id & 8191;
        const float* W = sel == 0 ? W0 : (sel == 1 ? W1 : W2);
        unsigned* O = sel == 0 ? O0 : (sel == 1 ? O1 : O2);
        O[l] = pack_bf2(W[2 * l], W[2 * l + 1]);
    }
}

// ---------------- CSR build: bucketed 2-phase counting sort ----------------

__global__ __launch_bounds__(256) void bucket_count_kernel(const int* __restrict__ dst,
                                                           int* __restrict__ gbucket,
                                                           int E, int NB) {
    __shared__ int hist[512];
    int t = threadIdx.x;
    for (int b = t; b < NB; b += 256) hist[b] = 0;
    __syncthreads();
    int base = blockIdx.x * 4096;
    #pragma unroll
    for (int j = 0; j < 16; ++j) {
        int e = base + j * 256 + t;
        if (e < E) atomicAdd(&hist[dst[e] >> BSH], 1);
    }
    __syncthreads();
    for (int b = t; b < NB; b += 256) {
        int v = hist[b];
        if (v) atomicAdd(&gbucket[b], v);
    }
}

__global__ void bucket_scan_kernel(const int* __restrict__ gbucket, int* __restrict__ bstart,
                                   int* __restrict__ gcur, int NB, int E) {
    __shared__ int sm[512];
    int t = threadIdx.x;
    int v = (t < NB) ? gbucket[t] : 0;
    sm[t] = v;
    __syncthreads();
    for (int off = 1; off < 512; off <<= 1) {
        int add = (t >= off) ? sm[t - off] : 0;
        __syncthreads();
        sm[t] += add;
        __syncthreads();
    }
    if (t < NB) {
        int ex = sm[t] - v;
        bstart[t] = ex;
        gcur[t] = ex;
    }
    if (t == 0) bstart[NB] = E;
}

__global__ __launch_bounds__(256) void bucket_scatter_kernel(const int* __restrict__ src,
                                                             const int* __restrict__ dst,
                                                             int* __restrict__ gcur,
                                                             uint2* __restrict__ staging,
                                                             int E, int NB) {
    __shared__ int hist[512];
    __shared__ int base[512];
    int t = threadIdx.x;
    for (int b = t; b < NB; b += 256) hist[b] = 0;
    __syncthreads();
    int s[16], d[16], r[16];
    int e0 = blockIdx.x * 4096;
    #pragma unroll
    for (int j = 0; j < 16; ++j) {
        int e = e0 + j * 256 + t;
        if (e < E) {
            s[j] = src[e];
            d[j] = dst[e];
            r[j] = atomicAdd(&hist[d[j] >> BSH], 1);
        } else d[j] = -1;
    }
    __syncthreads();
    for (int b = t; b < NB; b += 256) {
        int v = hist[b];
        base[b] = v ? atomicAdd(&gcur[b], v) : 0;
    }
    __syncthreads();
    #pragma unroll
    for (int j = 0; j < 16; ++j) {
        if (d[j] >= 0) {
            int b = d[j] >> BSH;
            staging[base[b] + r[j]] = make_uint2((unsigned)s[j], (unsigned)d[j]);
        }
    }
}

__global__ __launch_bounds__(256) void csr_build_kernel(const uint2* __restrict__ staging,
                                                        const int* __restrict__ bstart,
                                                        int* __restrict__ rp, int* __restrict__ csr,
                                                        float* __restrict__ degf,
                                                        int N, int E, int NB) {
    __shared__ int hist[256];
    __shared__ int sm[256];
    __shared__ int excl[256];
    __shared__ int cnt[256];
    int t = threadIdx.x;
    int b = blockIdx.x;
    int nbase = b << BSH;
    int s0 = bstart[b], e1 = bstart[b + 1];
    hist[t] = 0;
    __syncthreads();
    for (int i = s0 + t; i < e1; i += 256) {
        uint2 p = staging[i];
        atomicAdd(&hist[p.y & (BNODES - 1)], 1);
    }
    __syncthreads();
    int h = hist[t];
    sm[t] = h;
    __syncthreads();
    for (int off = 1; off < 256; off <<= 1) {
        int add = (t >= off) ? sm[t - off] : 0;
        __syncthreads();
        sm[t] += add;
        __syncthreads();
    }
    excl[t] = sm[t] - h;
    cnt[t] = 0;
    int n = nbase + t;
    if (n < N) {
        rp[n] = s0 + (sm[t] - h);
        degf[n] = (float)h;
    }
    if (b == NB - 1 && t == 0) rp[N] = E;
    __syncthreads();
    for (int i = s0 + t; i < e1; i += 256) {
        uint2 p = staging[i];
        int dl = p.y & (BNODES - 1);
        int pos = s0 + excl[dl] + atomicAdd(&cnt[dl], 1);
        csr[pos] = (int)p.x;
    }
}

// ---------------- h0 in fp8 (col0 zeroed; deg handled exactly via degf) ----------------

__global__ void build_h0_kernel(const float* __restrict__ feat,
                                unsigned* __restrict__ h8, int N) {
    int id = blockIdx.x * blockDim.x + threadIdx.x;
    if (id >= N * 32) return;
    int n = id >> 5, c = id & 31;
    const float* fr = feat + (size_t)n * NRAW;
    float f0, f1, f2, f3;
    if (c == 0) {
        f0 = 0.f;          // deg column handled exactly via degf in layer-0 agg
        f1 = fr[0]; f2 = fr[1]; f3 = fr[2];
    } else {
        int b = 4 * c - 1;
        f0 = fr[b]; f1 = fr[b + 1]; f2 = fr[b + 2]; f3 = fr[b + 3];
    }
    unsigned w = __builtin_amdgcn_cvt_pk_fp8_f32(f0, f1, 0, false);
    w = __builtin_amdgcn_cvt_pk_fp8_f32(f2, f3, w, true);
    h8[id] = w;
}

// ---------------- aggregation: fp8 gather, 4 nodes per wave, 16 lanes per node ----------------
// h8 [N][16] uint2 (=128 fp8 cols, 128 B/row). Each 16-lane group owns one node and walks
// its CSR segment serially (unroll 2). col = lane&15 selects the uint2 within the row.
// No cross-lane reduction needed. out bf16 [N][64] u32 (uint4 per lane).
// If degf != null (layer 0), col0 of the mean is exact from degf (col==0 lane accumulates).

__global__ __launch_bounds__(256) void agg_fp8_kernel(const unsigned* __restrict__ h8,
                                                      unsigned* __restrict__ agg,
                                                      const int* __restrict__ rp,
                                                      const int* __restrict__ csr,
                                                      const float* __restrict__ degf, int N) {
    int t = threadIdx.x;
    int col = t & 15;
    int i = blockIdx.x * 16 + (t >> 4);   // 16 nodes per 256-thread block
    if (i >= N) return;
    int start = rp[i], end = rp[i + 1];
    int deg = end - start;
    const uint2* h2 = (const uint2*)h8;
    if (deg == 0) {
        // keep old h: decode self fp8 row to bf16 (exact for zeroed deg col: true deg = 0)
        uint2 v = h2[(size_t)i * 16 + col];
        floatx2 l0 = __builtin_amdgcn_cvt_pk_f32_fp8(v.x, false);
        floatx2 h0 = __builtin_amdgcn_cvt_pk_f32_fp8(v.x, true);
        floatx2 l1 = __builtin_amdgcn_cvt_pk_f32_fp8(v.y, false);
        floatx2 h1 = __builtin_amdgcn_cvt_pk_f32_fp8(v.y, true);
        uint4 r;
        r.x = pack_bf2(l0[0], l0[1]);
        r.y = pack_bf2(h0[0], h0[1]);
        r.z = pack_bf2(l1[0], l1[1]);
        r.w = pack_bf2(h1[0], h1[1]);
        ((uint4*)agg)[(size_t)i * 16 + col] = r;
        return;
    }
    floatx2 a0 = {0.f, 0.f}, a1 = {0.f, 0.f}, a2 = {0.f, 0.f}, a3 = {0.f, 0.f};
    float dsum = 0.f;
    int p = start;
    for (; p + 2 <= end; p += 2) {
        int i0 = csr[p];
        int i1 = csr[p + 1];
        uint2 v0 = h2[(size_t)i0 * 16 + col];
        uint2 v1 = h2[(size_t)i1 * 16 + col];
        if (degf && col == 0) dsum += degf[i0] + degf[i1];
        a0 += __builtin_amdgcn_cvt_pk_f32_fp8(v0.x, false);
        a1 += __builtin_amdgcn_cvt_pk_f32_fp8(v0.x, true);
        a2 += __builtin_amdgcn_cvt_pk_f32_fp8(v0.y, false);
        a3 += __builtin_amdgcn_cvt_pk_f32_fp8(v0.y, true);
        a0 += __builtin_amdgcn_cvt_pk_f32_fp8(v1.x, false);
        a1 += __builtin_amdgcn_cvt_pk_f32_fp8(v1.x, true);
        a2 += __builtin_amdgcn_cvt_pk_f32_fp8(v1.y, false);
        a3 += __builtin_amdgcn_cvt_pk_f32_fp8(v1.y, true);
    }
    if (p < end) {
        int i0 = csr[p];
        uint2 v0 = h2[(size_t)i0 * 16 + col];
        if (degf && col == 0) dsum += degf[i0];
        a0 += __builtin_amdgcn_cvt_pk_f32_fp8(v0.x, false);
        a1 += __builtin_amdgcn_cvt_pk_f32_fp8(v0.x, true);
        a2 += __builtin_amdgcn_cvt_pk_f32_fp8(v0.y, false);
        a3 += __builtin_amdgcn_cvt_pk_f32_fp8(v0.y, true);
    }
    if (degf && col == 0) a0[0] = dsum;   // exact neighbor-deg sum -> column 0
    float inv = 1.f / (float)deg;
    uint4 r;
    r.x = pack_bf2(a0[0] * inv, a0[1] * inv);
    r.y = pack_bf2(a1[0] * inv, a1[1] * inv);
    r.z = pack_bf2(a2[0] * inv, a2[1] * inv);
    r.w = pack_bf2(a3[0] * inv, a3[1] * inv);
    ((uint4*)agg)[(size_t)i * 16 + col] = r;
}

// ---------------- GEMM: relu(A @ W^T + b) via MFMA bf16; out fp8 and/or bf16 ----------------
// A [N,128] bf16, Wb [128,128] bf16. 16x16x32 layouts: A/B lane = [idx=lane&15][k=(lane>>4)*8+j];
// C/D: col = lane&15, row = (lane>>4)*4 + reg.

__global__ __launch_bounds__(256) void mfma_gemm_kernel(const unsigned* __restrict__ A,
                                                        unsigned* __restrict__ out8,
                                                        unsigned* __restrict__ outb,
                                                        const unsigned* __restrict__ Wb,
                                                        const float* __restrict__ bias, int N) {
    __shared__ unsigned Al[64 * APAD];
    int t = threadIdx.x;
    int n0 = blockIdx.x * 64;
    #pragma unroll
    for (int c = 0; c < 4; ++c) {
        int f = c * 256 + t;
        int row = f >> 4, c4 = f & 15;
        int n = n0 + row;
        uint4 v = make_uint4(0u, 0u, 0u, 0u);
        if (n < N) v = ((const uint4*)A)[(size_t)n * 16 + c4];
        *(uint4*)&Al[row * APAD + c4 * 4] = v;
    }
    __syncthreads();

    int wv = t >> 6, lane = t & 63;
    int m = lane & 15, q = lane >> 4;
    floatx4 acc[8];
    #pragma unroll
    for (int ot = 0; ot < 8; ++ot) acc[ot] = (floatx4)(0.f);

    #pragma unroll
    for (int kt = 0; kt < 4; ++kt) {
        short8 af = *(const short8*)&Al[(wv * 16 + m) * APAD + kt * 16 + q * 4];
        short8 bf[8];
        #pragma unroll
        for (int ot = 0; ot < 8; ++ot)
            bf[ot] = *(const short8*)&Wb[(ot * 16 + m) * 64 + kt * 16 + q * 4];
        #pragma unroll
        for (int ot = 0; ot < 8; ++ot)
            acc[ot] = __builtin_amdgcn_mfma_f32_16x16x32_bf16(af, bf[ot], acc[ot], 0, 0, 0);
    }

    unsigned short* oh = (unsigned short*)outb;
    unsigned char* o8 = (unsigned char*)out8;
    #pragma unroll
    for (int ot = 0; ot < 8; ++ot) {
        int o = ot * 16 + m;
        float bv = bias[o];
        #pragma unroll
        for (int r = 0; r < 4; ++r) {
            int n = n0 + wv * 16 + q * 4 + r;
            if (n < N) {
                float v = fmaxf(acc[ot][r] + bv, 0.f);
                if (outb) {
                    unsigned bx = __float_as_uint(v);
                    bx += 0x7fffu + ((bx >> 16) & 1u);
                    oh[(size_t)n * 128 + o] = (unsigned short)(bx >> 16);
                }
                if (out8) {
                    unsigned pk = __builtin_amdgcn_cvt_pk_fp8_f32(v, v, 0, false);
                    o8[(size_t)n * 128 + o] = (unsigned char)(pk & 0xffu);
                }
            }
        }
    }
}

// ---------------- graph mean-pool + counts (merged) ----------------

__global__ void pool_kernel(const unsigned* __restrict__ h, const int* __restrict__ gid,
                            float* __restrict__ hg, float* __restrict__ counts, int N) {
    int c = threadIdx.x & 63;
    int half = threadIdx.x >> 6;
    int n0 = blockIdx.x * 512;
    int nend = min(n0 + 512, N);
    float ax = 0.f, ay = 0.f, cnt = 0.f;
    int cur = -1;
    for (int n = n0 + half; n < nend; n += 4) {
        int g = gid[n];
        if (g != cur) {
            if (cur >= 0) {
                atomicAdd(&hg[cur * HID + 2 * c], ax);
                atomicAdd(&hg[cur * HID + 2 * c + 1], ay);
                if (c == 0) atomicAdd(&counts[cur], cnt);
            }
            ax = ay = cnt = 0.f;
            cur = g;
        }
        unsigned v = h[(size_t)n * 64 + c];
        ax += bf_lo(v); ay += bf_hi(v);
        cnt += 1.f;
    }
    if (cur >= 0) {
        atomicAdd(&hg[cur * HID + 2 * c], ax);
        atomicAdd(&hg[cur * HID + 2 * c + 1], ay);
        if (c == 0) atomicAdd(&counts[cur], cnt);
    }
}

// ---------------- fused classifier head (fp32), one block per graph ----------------

__global__ __launch_bounds__(128) void cls_fused_kernel(const float* __restrict__ hg,
                                                        const float* __restrict__ counts,
                                                        const float* __restrict__ Wc1,
                                                        const float* __restrict__ bc1,
                                                        const float* __restrict__ Wc2,
                                                        const float* __restrict__ bc2,
                                                        float* __restrict__ out, int G) {
    __shared__ float x[128];
    __shared__ float y[128];
    __shared__ float red[128];
    int g = blockIdx.x, t = threadIdx.x;
    float inv = 1.f / fmaxf(counts[g], 1.f);
    x[t] = hg[g * HID + t] * inv;
    __syncthreads();
    const float4* w4 = (const float4*)(Wc1 + t * HID);
    float s = 0.f;
    #pragma unroll
    for (int k4 = 0; k4 < 32; ++k4) {
        float4 w = w4[k4];
        s += x[k4 * 4] * w.x + x[k4 * 4 + 1] * w.y + x[k4 * 4 + 2] * w.z + x[k4 * 4 + 3] * w.w;
    }
    y[t] = s + bc1[t];
    __syncthreads();
    float s2 = 0.f;
    #pragma unroll
    for (int k4 = 0; k4 < 32; ++k4) {
        float4 w = w4[k4];
        s2 += y[k4 * 4] * w.x + y[k4 * 4 + 1] * w.y + y[k4 * 4 + 2] * w.z + y[k4 * 4 + 3] * w.w;
    }
    red[t] = (s2 + bc1[t]) * Wc2[t];
    __syncthreads();
    if (t < 64) {
        float r = red[t] + red[t + 64];
        #pragma unroll
        for (int off = 32; off > 0; off >>= 1) r += __shfl_down(r, off);
        if (t == 0) out[g] = r + bc2[0];
    }
}

// ---------------- launch ----------------

extern "C" void kernel_launch(void* const* d_in, const int* in_sizes, int n_in,
                              void* d_out, int out_size, void* d_ws, size_t ws_size,
                              hipStream_t stream) {
    const float* feat = (const float*)d_in[0];
    const int* src    = (const int*)d_in[1];
    const int* dst    = (const int*)d_in[2];
    const int* gid    = (const int*)d_in[3];
    const float* W0  = (const float*)d_in[5];
    const float* b0  = (const float*)d_in[6];
    const float* W1  = (const float*)d_in[7];
    const float* b1  = (const float*)d_in[8];
    const float* W2  = (const float*)d_in[9];
    const float* b2  = (const float*)d_in[10];
    const float* Wc1 = (const float*)d_in[11];
    const float* bc1 = (const float*)d_in[12];
    const float* Wc2 = (const float*)d_in[13];
    const float* bc2 = (const float*)d_in[14];

    const int N = in_sizes[3];
    const int E = in_sizes[1];
    const int G = out_size;
    const int NB = (N + BNODES - 1) >> BSH;

    char* ws = (char*)d_ws;
    size_t off = 0;
    auto alloc = [&](size_t bytes) { void* p = ws + off; off += (bytes + 255) & ~size_t(255); return p; };
    unsigned* h8     = (unsigned*)alloc((size_t)N * 32 * 4);   // fp8 h (h0 -> h1 -> h2, reused)
    unsigned* hB     = (unsigned*)alloc((size_t)N * 64 * 4);   // bf16 h3 for pool
    unsigned* aggbuf = (unsigned*)alloc((size_t)N * 64 * 4);   // bf16 GEMM input
    float* degf      = (float*)alloc((size_t)N * 4);
    uint2* staging   = (uint2*)alloc((size_t)E * 8);
    int* csr         = (int*)alloc((size_t)E * 4);
    int* rp          = (int*)alloc((size_t)(N + 1) * 4);
    int* gbucket     = (int*)alloc(512 * 4);
    int* bstart      = (int*)alloc(513 * 4);
    int* gcur        = (int*)alloc(512 * 4);
    unsigned* Wb0    = (unsigned*)alloc(8192 * 4);
    unsigned* Wb1    = (unsigned*)alloc(8192 * 4);
    unsigned* Wb2    = (unsigned*)alloc(8192 * 4);
    float* hg        = (float*)alloc((size_t)G * HID * 4);
    float* counts    = (float*)alloc((size_t)G * 4);

    init_kernel<<<96, 256, 0, stream>>>(W0, W1, W2, Wb0, Wb1, Wb2, gbucket, hg, counts, G);

    int gE = (E + 4095) / 4096;
    bucket_count_kernel<<<gE, 256, 0, stream>>>(dst, gbucket, E, NB);
    bucket_scan_kernel<<<1, 512, 0, stream>>>(gbucket, bstart, gcur, NB, E);
    bucket_scatter_kernel<<<gE, 256, 0, stream>>>(src, dst, gcur, staging, E, NB);
    csr_build_kernel<<<NB, 256, 0, stream>>>(staging, bstart, rp, csr, degf, N, E, NB);

    build_h0_kernel<<<(N * 32 + 255) / 256, 256, 0, stream>>>(feat, h8, N);

    int agg_grid = (N + 15) / 16;
    int gemm_grid = (N + 63) / 64;

    agg_fp8_kernel<<<agg_grid, 256, 0, stream>>>(h8, aggbuf, rp, csr, degf, N);
    mfma_gemm_kernel<<<gemm_grid, 256, 0, stream>>>(aggbuf, h8, nullptr, Wb0, b0, N);

    agg_fp8_kernel<<<agg_grid, 256, 0, stream>>>(h8, aggbuf, rp, csr, nullptr, N);
    mfma_gemm_kernel<<<gemm_grid, 256, 0, stream>>>(aggbuf, h8, nullptr, Wb1, b1, N);

    agg_fp8_kernel<<<agg_grid, 256, 0, stream>>>(h8, aggbuf, rp, csr, nullptr, N);
    mfma_gemm_kernel<<<gemm_grid, 256, 0, stream>>>(aggbuf, nullptr, hB, Wb2, b2, N);

    pool_kernel<<<(N + 511) / 512, 256, 0, stream>>>(hB, gid, hg, counts, N);

    cls_fused_kernel<<<G, 128, 0, stream>>>(hg, counts, Wc1, bc1, Wc2, bc2, (float*)d_out, G);
}

// Round 8
// 448.442 us; speedup vs baseline: 1.5946x; 1.0540x over previous
//
#include <hip/hip_runtime.h>
#include <hip/hip_bf16.h>

#define HID 128
#define NRAW 127
#define BSH 8          // 256 nodes per bucket
#define BNODES 256
#define APAD 68        // LDS row pitch in u32 (16B-aligned, breaks pow2 stride)

typedef __attribute__((ext_vector_type(8))) short short8;
typedef __attribute__((ext_vector_type(4))) float floatx4;
typedef __attribute__((ext_vector_type(2))) float floatx2;

__device__ inline unsigned pack_bf2(float x, float y) {
    unsigned bx = __float_as_uint(x);
    unsigned by = __float_as_uint(y);
    bx += 0x7fffu + ((bx >> 16) & 1u);   // RNE
    by += 0x7fffu + ((by >> 16) & 1u);
    return (bx >> 16) | (by & 0xffff0000u);
}
__device__ inline float bf_lo(unsigned u) { return __uint_as_float(u << 16); }
__device__ inline float bf_hi(unsigned u) { return __uint_as_float(u & 0xffff0000u); }

// ---------------- init: zeros + weight bf16 pack ----------------

__global__ void init_kernel(const float* __restrict__ W0, const float* __restrict__ W1,
                            const float* __restrict__ W2,
                            unsigned* __restrict__ O0, unsigned* __restrict__ O1,
                            unsigned* __restrict__ O2,
                            int* __restrict__ gbucket, float* __restrict__ hg,
                            float* __restrict__ counts, int G) {
    int id = blockIdx.x * blockDim.x + threadIdx.x;
    if (id < 512) gbucket[id] = 0;
    if (id < G * HID) hg[id] = 0.f;
    if (id < G) counts[id] = 0.f;
    if (id < 3 * 8192) {
        int sel = id >> 13, l = id & 8191;
        const float* W = sel == 0 ? W0 : (sel == 1 ? W1 : W2);
        unsigned* O = sel == 0 ? O0 : (sel == 1 ? O1 : O2);
        O[l] = pack_bf2(W[2 * l], W[2 * l + 1]);
    }
}

// ---------------- CSR build: bucketed 2-phase counting sort ----------------

__global__ __launch_bounds__(256) void bucket_count_kernel(const int* __restrict__ dst,
                                                           int* __restrict__ gbucket,
                                                           int E, int NB) {
    __shared__ int hist[512];
    int t = threadIdx.x;
    for (int b = t; b < NB; b += 256) hist[b] = 0;
    __syncthreads();
    int base = blockIdx.x * 4096;
    #pragma unroll
    for (int j = 0; j < 16; ++j) {
        int e = base + j * 256 + t;
        if (e < E) atomicAdd(&hist[dst[e] >> BSH], 1);
    }
    __syncthreads();
    for (int b = t; b < NB; b += 256) {
        int v = hist[b];
        if (v) atomicAdd(&gbucket[b], v);
    }
}

__global__ void bucket_scan_kernel(const int* __restrict__ gbucket, int* __restrict__ bstart,
                                   int* __restrict__ gcur, int NB, int E) {
    __shared__ int sm[512];
    int t = threadIdx.x;
    int v = (t < NB) ? gbucket[t] : 0;
    sm[t] = v;
    __syncthreads();
    for (int off = 1; off < 512; off <<= 1) {
        int add = (t >= off) ? sm[t - off] : 0;
        __syncthreads();
        sm[t] += add;
        __syncthreads();
    }
    if (t < NB) {
        int ex = sm[t] - v;
        bstart[t] = ex;
        gcur[t] = ex;
    }
    if (t == 0) bstart[NB] = E;
}

__global__ __launch_bounds__(256) void bucket_scatter_kernel(const int* __restrict__ src,
                                                             const int* __restrict__ dst,
                                                             int* __restrict__ gcur,
                                                             uint2* __restrict__ staging,
                                                             int E, int NB) {
    __shared__ int hist[512];
    __shared__ int base[512];
    int t = threadIdx.x;
    for (int b = t; b < NB; b += 256) hist[b] = 0;
    __syncthreads();
    int s[16], d[16], r[16];
    int e0 = blockIdx.x * 4096;
    #pragma unroll
    for (int j = 0; j < 16; ++j) {
        int e = e0 + j * 256 + t;
        if (e < E) {
            s[j] = src[e];
            d[j] = dst[e];
            r[j] = atomicAdd(&hist[d[j] >> BSH], 1);
        } else d[j] = -1;
    }
    __syncthreads();
    for (int b = t; b < NB; b += 256) {
        int v = hist[b];
        base[b] = v ? atomicAdd(&gcur[b], v) : 0;
    }
    __syncthreads();
    #pragma unroll
    for (int j = 0; j < 16; ++j) {
        if (d[j] >= 0) {
            int b = d[j] >> BSH;
            staging[base[b] + r[j]] = make_uint2((unsigned)s[j], (unsigned)d[j]);
        }
    }
}

__global__ __launch_bounds__(256) void csr_build_kernel(const uint2* __restrict__ staging,
                                                        const int* __restrict__ bstart,
                                                        int* __restrict__ rp, int* __restrict__ csr,
                                                        float* __restrict__ degf,
                                                        int N, int E, int NB) {
    __shared__ int hist[256];
    __shared__ int sm[256];
    __shared__ int excl[256];
    __shared__ int cnt[256];
    int t = threadIdx.x;
    int b = blockIdx.x;
    int nbase = b << BSH;
    int s0 = bstart[b], e1 = bstart[b + 1];
    hist[t] = 0;
    __syncthreads();
    for (int i = s0 + t; i < e1; i += 256) {
        uint2 p = staging[i];
        atomicAdd(&hist[p.y & (BNODES - 1)], 1);
    }
    __syncthreads();
    int h = hist[t];
    sm[t] = h;
    __syncthreads();
    for (int off = 1; off < 256; off <<= 1) {
        int add = (t >= off) ? sm[t - off] : 0;
        __syncthreads();
        sm[t] += add;
        __syncthreads();
    }
    excl[t] = sm[t] - h;
    cnt[t] = 0;
    int n = nbase + t;
    if (n < N) {
        rp[n] = s0 + (sm[t] - h);
        degf[n] = (float)h;
    }
    if (b == NB - 1 && t == 0) rp[N] = E;
    __syncthreads();
    for (int i = s0 + t; i < e1; i += 256) {
        uint2 p = staging[i];
        int dl = p.y & (BNODES - 1);
        int pos = s0 + excl[dl] + atomicAdd(&cnt[dl], 1);
        csr[pos] = (int)p.x;
    }
}

// ---------------- h0 in fp8 (col0 zeroed; deg handled exactly via degf) ----------------

__global__ void build_h0_kernel(const float* __restrict__ feat,
                                unsigned* __restrict__ h8, int N) {
    int id = blockIdx.x * blockDim.x + threadIdx.x;
    if (id >= N * 32) return;
    int n = id >> 5, c = id & 31;
    const float* fr = feat + (size_t)n * NRAW;
    float f0, f1, f2, f3;
    if (c == 0) {
        f0 = 0.f;          // deg column handled exactly via degf in layer-0 agg
        f1 = fr[0]; f2 = fr[1]; f3 = fr[2];
    } else {
        int b = 4 * c - 1;
        f0 = fr[b]; f1 = fr[b + 1]; f2 = fr[b + 2]; f3 = fr[b + 3];
    }
    unsigned w = __builtin_amdgcn_cvt_pk_fp8_f32(f0, f1, 0, false);
    w = __builtin_amdgcn_cvt_pk_fp8_f32(f2, f3, w, true);
    h8[id] = w;
}

// ---------------- aggregation: fp8 gather, 16 lanes per node, unroll-4 ----------------
// h8 [N][16] uint2 (=128 fp8 cols, 128 B/row). Each 16-lane group owns one node and walks
// its CSR segment with 4 rows in flight. col = lane&15 selects the uint2 within the row.
// No cross-lane reduction. out bf16 [N][64] u32 (uint4 per lane).
// If degf != null (layer 0), col0 of the mean is exact from degf (col==0 lane accumulates).

__global__ __launch_bounds__(256) void agg_fp8_kernel(const unsigned* __restrict__ h8,
                                                      unsigned* __restrict__ agg,
                                                      const int* __restrict__ rp,
                                                      const int* __restrict__ csr,
                                                      const float* __restrict__ degf, int N) {
    int t = threadIdx.x;
    int col = t & 15;
    int i = blockIdx.x * 16 + (t >> 4);   // 16 nodes per 256-thread block
    if (i >= N) return;
    int start = rp[i], end = rp[i + 1];
    int deg = end - start;
    const uint2* h2 = (const uint2*)h8;
    if (deg == 0) {
        // keep old h: decode self fp8 row to bf16 (exact for zeroed deg col: true deg = 0)
        uint2 v = h2[(size_t)i * 16 + col];
        floatx2 l0 = __builtin_amdgcn_cvt_pk_f32_fp8(v.x, false);
        floatx2 h0 = __builtin_amdgcn_cvt_pk_f32_fp8(v.x, true);
        floatx2 l1 = __builtin_amdgcn_cvt_pk_f32_fp8(v.y, false);
        floatx2 h1 = __builtin_amdgcn_cvt_pk_f32_fp8(v.y, true);
        uint4 r;
        r.x = pack_bf2(l0[0], l0[1]);
        r.y = pack_bf2(h0[0], h0[1]);
        r.z = pack_bf2(l1[0], l1[1]);
        r.w = pack_bf2(h1[0], h1[1]);
        ((uint4*)agg)[(size_t)i * 16 + col] = r;
        return;
    }
    floatx2 a0 = {0.f, 0.f}, a1 = {0.f, 0.f}, a2 = {0.f, 0.f}, a3 = {0.f, 0.f};
    float dsum = 0.f;
    int p = start;
    for (; p + 4 <= end; p += 4) {
        int i0 = csr[p];
        int i1 = csr[p + 1];
        int i2 = csr[p + 2];
        int i3 = csr[p + 3];
        uint2 v0 = h2[(size_t)i0 * 16 + col];
        uint2 v1 = h2[(size_t)i1 * 16 + col];
        uint2 v2 = h2[(size_t)i2 * 16 + col];
        uint2 v3 = h2[(size_t)i3 * 16 + col];
        if (degf && col == 0) dsum += degf[i0] + degf[i1] + degf[i2] + degf[i3];
        a0 += __builtin_amdgcn_cvt_pk_f32_fp8(v0.x, false);
        a1 += __builtin_amdgcn_cvt_pk_f32_fp8(v0.x, true);
        a2 += __builtin_amdgcn_cvt_pk_f32_fp8(v0.y, false);
        a3 += __builtin_amdgcn_cvt_pk_f32_fp8(v0.y, true);
        a0 += __builtin_amdgcn_cvt_pk_f32_fp8(v1.x, false);
        a1 += __builtin_amdgcn_cvt_pk_f32_fp8(v1.x, true);
        a2 += __builtin_amdgcn_cvt_pk_f32_fp8(v1.y, false);
        a3 += __builtin_amdgcn_cvt_pk_f32_fp8(v1.y, true);
        a0 += __builtin_amdgcn_cvt_pk_f32_fp8(v2.x, false);
        a1 += __builtin_amdgcn_cvt_pk_f32_fp8(v2.x, true);
        a2 += __builtin_amdgcn_cvt_pk_f32_fp8(v2.y, false);
        a3 += __builtin_amdgcn_cvt_pk_f32_fp8(v2.y, true);
        a0 += __builtin_amdgcn_cvt_pk_f32_fp8(v3.x, false);
        a1 += __builtin_amdgcn_cvt_pk_f32_fp8(v3.x, true);
        a2 += __builtin_amdgcn_cvt_pk_f32_fp8(v3.y, false);
        a3 += __builtin_amdgcn_cvt_pk_f32_fp8(v3.y, true);
    }
    for (; p < end; ++p) {
        int i0 = csr[p];
        uint2 v0 = h2[(size_t)i0 * 16 + col];
        if (degf && col == 0) dsum += degf[i0];
        a0 += __builtin_amdgcn_cvt_pk_f32_fp8(v0.x, false);
        a1 += __builtin_amdgcn_cvt_pk_f32_fp8(v0.x, true);
        a2 += __builtin_amdgcn_cvt_pk_f32_fp8(v0.y, false);
        a3 += __builtin_amdgcn_cvt_pk_f32_fp8(v0.y, true);
    }
    if (degf && col == 0) a0[0] = dsum;   // exact neighbor-deg sum -> column 0
    float inv = 1.f / (float)deg;
    uint4 r;
    r.x = pack_bf2(a0[0] * inv, a0[1] * inv);
    r.y = pack_bf2(a1[0] * inv, a1[1] * inv);
    r.z = pack_bf2(a2[0] * inv, a2[1] * inv);
    r.w = pack_bf2(a3[0] * inv, a3[1] * inv);
    ((uint4*)agg)[(size_t)i * 16 + col] = r;
}

// ---------------- GEMM: relu(A @ W^T + b) via MFMA bf16; out fp8 and/or bf16 ----------------
// A [N,128] bf16, Wb [128,128] bf16. 16x16x32 layouts: A/B lane = [idx=lane&15][k=(lane>>4)*8+j];
// C/D: col = lane&15, row = (lane>>4)*4 + reg.

__global__ __launch_bounds__(256) void mfma_gemm_kernel(const unsigned* __restrict__ A,
                                                        unsigned* __restrict__ out8,
                                                        unsigned* __restrict__ outb,
                                                        const unsigned* __restrict__ Wb,
                                                        const float* __restrict__ bias, int N) {
    __shared__ unsigned Al[64 * APAD];
    int t = threadIdx.x;
    int n0 = blockIdx.x * 64;
    #pragma unroll
    for (int c = 0; c < 4; ++c) {
        int f = c * 256 + t;
        int row = f >> 4, c4 = f & 15;
        int n = n0 + row;
        uint4 v = make_uint4(0u, 0u, 0u, 0u);
        if (n < N) v = ((const uint4*)A)[(size_t)n * 16 + c4];
        *(uint4*)&Al[row * APAD + c4 * 4] = v;
    }
    __syncthreads();

    int wv = t >> 6, lane = t & 63;
    int m = lane & 15, q = lane >> 4;
    floatx4 acc[8];
    #pragma unroll
    for (int ot = 0; ot < 8; ++ot) acc[ot] = (floatx4)(0.f);

    #pragma unroll
    for (int kt = 0; kt < 4; ++kt) {
        short8 af = *(const short8*)&Al[(wv * 16 + m) * APAD + kt * 16 + q * 4];
        short8 bf[8];
        #pragma unroll
        for (int ot = 0; ot < 8; ++ot)
            bf[ot] = *(const short8*)&Wb[(ot * 16 + m) * 64 + kt * 16 + q * 4];
        #pragma unroll
        for (int ot = 0; ot < 8; ++ot)
            acc[ot] = __builtin_amdgcn_mfma_f32_16x16x32_bf16(af, bf[ot], acc[ot], 0, 0, 0);
    }

    unsigned short* oh = (unsigned short*)outb;
    unsigned char* o8 = (unsigned char*)out8;
    #pragma unroll
    for (int ot = 0; ot < 8; ++ot) {
        int o = ot * 16 + m;
        float bv = bias[o];
        #pragma unroll
        for (int r = 0; r < 4; ++r) {
            int n = n0 + wv * 16 + q * 4 + r;
            if (n < N) {
                float v = fmaxf(acc[ot][r] + bv, 0.f);
                if (outb) {
                    unsigned bx = __float_as_uint(v);
                    bx += 0x7fffu + ((bx >> 16) & 1u);
                    oh[(size_t)n * 128 + o] = (unsigned short)(bx >> 16);
                }
                if (out8) {
                    unsigned pk = __builtin_amdgcn_cvt_pk_fp8_f32(v, v, 0, false);
                    o8[(size_t)n * 128 + o] = (unsigned char)(pk & 0xffu);
                }
            }
        }
    }
}

// ---------------- graph mean-pool + counts: 64-node blocks, 4-way node striping ----------------

__global__ __launch_bounds__(256) void pool_kernel(const unsigned* __restrict__ h,
                                                   const int* __restrict__ gid,
                                                   float* __restrict__ hg,
                                                   float* __restrict__ counts, int N) {
    int c = threadIdx.x & 63;
    int q = threadIdx.x >> 6;
    int n0 = blockIdx.x * 64;
    int nend = min(n0 + 64, N);
    float ax = 0.f, ay = 0.f, cnt = 0.f;
    int cur = -1;
    for (int n = n0 + q; n < nend; n += 4) {
        int g = gid[n];
        if (g != cur) {
            if (cur >= 0) {
                atomicAdd(&hg[cur * HID + 2 * c], ax);
                atomicAdd(&hg[cur * HID + 2 * c + 1], ay);
                if (c == 0) atomicAdd(&counts[cur], cnt);
            }
            ax = ay = cnt = 0.f;
            cur = g;
        }
        unsigned v = h[(size_t)n * 64 + c];
        ax += bf_lo(v); ay += bf_hi(v);
        cnt += 1.f;
    }
    if (cur >= 0) {
        atomicAdd(&hg[cur * HID + 2 * c], ax);
        atomicAdd(&hg[cur * HID + 2 * c + 1], ay);
        if (c == 0) atomicAdd(&counts[cur], cnt);
    }
}

// ---------------- fused classifier head (fp32), one block per graph ----------------

__global__ __launch_bounds__(128) void cls_fused_kernel(const float* __restrict__ hg,
                                                        const float* __restrict__ counts,
                                                        const float* __restrict__ Wc1,
                                                        const float* __restrict__ bc1,
                                                        const float* __restrict__ Wc2,
                                                        const float* __restrict__ bc2,
                                                        float* __restrict__ out, int G) {
    __shared__ float x[128];
    __shared__ float y[128];
    __shared__ float red[128];
    int g = blockIdx.x, t = threadIdx.x;
    float inv = 1.f / fmaxf(counts[g], 1.f);
    x[t] = hg[g * HID + t] * inv;
    __syncthreads();
    const float4* w4 = (const float4*)(Wc1 + t * HID);
    float s = 0.f;
    #pragma unroll
    for (int k4 = 0; k4 < 32; ++k4) {
        float4 w = w4[k4];
        s += x[k4 * 4] * w.x + x[k4 * 4 + 1] * w.y + x[k4 * 4 + 2] * w.z + x[k4 * 4 + 3] * w.w;
    }
    y[t] = s + bc1[t];
    __syncthreads();
    float s2 = 0.f;
    #pragma unroll
    for (int k4 = 0; k4 < 32; ++k4) {
        float4 w = w4[k4];
        s2 += y[k4 * 4] * w.x + y[k4 * 4 + 1] * w.y + y[k4 * 4 + 2] * w.z + y[k4 * 4 + 3] * w.w;
    }
    red[t] = (s2 + bc1[t]) * Wc2[t];
    __syncthreads();
    if (t < 64) {
        float r = red[t] + red[t + 64];
        #pragma unroll
        for (int off = 32; off > 0; off >>= 1) r += __shfl_down(r, off);
        if (t == 0) out[g] = r + bc2[0];
    }
}

// ---------------- launch ----------------

extern "C" void kernel_launch(void* const* d_in, const int* in_sizes, int n_in,
                              void* d_out, int out_size, void* d_ws, size_t ws_size,
                              hipStream_t stream) {
    const float* feat = (const float*)d_in[0];
    const int* src    = (const int*)d_in[1];
    const int* dst    = (const int*)d_in[2];
    const int* gid    = (const int*)d_in[3];
    const float* W0  = (const float*)d_in[5];
    const float* b0  = (const float*)d_in[6];
    const float* W1  = (const float*)d_in[7];
    const float* b1  = (const float*)d_in[8];
    const float* W2  = (const float*)d_in[9];
    const float* b2  = (const float*)d_in[10];
    const float* Wc1 = (const float*)d_in[11];
    const float* bc1 = (const float*)d_in[12];
    const float* Wc2 = (const float*)d_in[13];
    const float* bc2 = (const float*)d_in[14];

    const int N = in_sizes[3];
    const int E = in_sizes[1];
    const int G = out_size;
    const int NB = (N + BNODES - 1) >> BSH;

    char* ws = (char*)d_ws;
    size_t off = 0;
    auto alloc = [&](size_t bytes) { void* p = ws + off; off += (bytes + 255) & ~size_t(255); return p; };
    unsigned* h8     = (unsigned*)alloc((size_t)N * 32 * 4);   // fp8 h (h0 -> h1 -> h2, reused)
    unsigned* hB     = (unsigned*)alloc((size_t)N * 64 * 4);   // bf16 h3 for pool
    unsigned* aggbuf = (unsigned*)alloc((size_t)N * 64 * 4);   // bf16 GEMM input
    float* degf      = (float*)alloc((size_t)N * 4);
    uint2* staging   = (uint2*)alloc((size_t)E * 8);
    int* csr         = (int*)alloc((size_t)E * 4);
    int* rp          = (int*)alloc((size_t)(N + 1) * 4);
    int* gbucket     = (int*)alloc(512 * 4);
    int* bstart      = (int*)alloc(513 * 4);
    int* gcur        = (int*)alloc(512 * 4);
    unsigned* Wb0    = (unsigned*)alloc(8192 * 4);
    unsigned* Wb1    = (unsigned*)alloc(8192 * 4);
    unsigned* Wb2    = (unsigned*)alloc(8192 * 4);
    float* hg        = (float*)alloc((size_t)G * HID * 4);
    float* counts    = (float*)alloc((size_t)G * 4);

    init_kernel<<<96, 256, 0, stream>>>(W0, W1, W2, Wb0, Wb1, Wb2, gbucket, hg, counts, G);

    int gE = (E + 4095) / 4096;
    bucket_count_kernel<<<gE, 256, 0, stream>>>(dst, gbucket, E, NB);
    bucket_scan_kernel<<<1, 512, 0, stream>>>(gbucket, bstart, gcur, NB, E);
    bucket_scatter_kernel<<<gE, 256, 0, stream>>>(src, dst, gcur, staging, E, NB);
    csr_build_kernel<<<NB, 256, 0, stream>>>(staging, bstart, rp, csr, degf, N, E, NB);

    build_h0_kernel<<<(N * 32 + 255) / 256, 256, 0, stream>>>(feat, h8, N);

    int agg_grid = (N + 15) / 16;
    int gemm_grid = (N + 63) / 64;

    agg_fp8_kernel<<<agg_grid, 256, 0, stream>>>(h8, aggbuf, rp, csr, degf, N);
    mfma_gemm_kernel<<<gemm_grid, 256, 0, stream>>>(aggbuf, h8, nullptr, Wb0, b0, N);

    agg_fp8_kernel<<<agg_grid, 256, 0, stream>>>(h8, aggbuf, rp, csr, nullptr, N);
    mfma_gemm_kernel<<<gemm_grid, 256, 0, stream>>>(aggbuf, h8, nullptr, Wb1, b1, N);

    agg_fp8_kernel<<<agg_grid, 256, 0, stream>>>(h8, aggbuf, rp, csr, nullptr, N);
    mfma_gemm_kernel<<<gemm_grid, 256, 0, stream>>>(aggbuf, nullptr, hB, Wb2, b2, N);

    pool_kernel<<<(N + 63) / 64, 256, 0, stream>>>(hB, gid, hg, counts, N);

    cls_fused_kernel<<<G, 128, 0, stream>>>(hg, counts, Wc1, bc1, Wc2, bc2, (float*)d_out, G);
}

// Round 9
// 431.708 us; speedup vs baseline: 1.6564x; 1.0388x over previous
//
#include <hip/hip_runtime.h>
#include <hip/hip_bf16.h>

#define HID 128
#define NRAW 127
#define BSH 8          // 256 nodes per bucket
#define BNODES 256
#define APAD 68        // LDS row pitch in u32 (16B-aligned, breaks pow2 stride)

// Column permutation: all hidden-state tensors (h8, aggbuf, hB, hg) store logical
// column l = ot*16+m at physical position p = m*8+ot  (p: pi(l)); inverse
// invp(p) = (p&7)*16 + (p>>3). GEMM weights and the first Wc1 application are
// k-permuted to match, so results are bit-identical to the unpermuted pipeline.

typedef __attribute__((ext_vector_type(8))) short short8;
typedef __attribute__((ext_vector_type(4))) float floatx4;
typedef __attribute__((ext_vector_type(2))) float floatx2;

__device__ inline unsigned pack_bf2(float x, float y) {
    unsigned bx = __float_as_uint(x);
    unsigned by = __float_as_uint(y);
    bx += 0x7fffu + ((bx >> 16) & 1u);   // RNE
    by += 0x7fffu + ((by >> 16) & 1u);
    return (bx >> 16) | (by & 0xffff0000u);
}
__device__ inline float bf_lo(unsigned u) { return __uint_as_float(u << 16); }
__device__ inline float bf_hi(unsigned u) { return __uint_as_float(u & 0xffff0000u); }

// ---------------- init: zeros + permuted weight packs ----------------

__global__ void init_kernel(const float* __restrict__ W0, const float* __restrict__ W1,
                            const float* __restrict__ W2, const float* __restrict__ Wc1,
                            unsigned* __restrict__ O0, unsigned* __restrict__ O1,
                            unsigned* __restrict__ O2, float* __restrict__ Wc1p,
                            int* __restrict__ gbucket, float* __restrict__ hg,
                            float* __restrict__ counts, int G) {
    int id = blockIdx.x * blockDim.x + threadIdx.x;
    if (id < 512) gbucket[id] = 0;
    if (id < G * HID) hg[id] = 0.f;
    if (id < G) counts[id] = 0.f;
    if (id < 16384) {   // Wc1 with permuted k for the first head matmul
        int t = id >> 7, p = id & 127;
        Wc1p[id] = Wc1[t * 128 + ((p & 7) * 16 + (p >> 3))];
    }
    if (id < 3 * 8192) {   // GCN weights, bf16, k-permuted
        int sel = id >> 13, l = id & 8191;
        const float* W = sel == 0 ? W0 : (sel == 1 ? W1 : W2);
        unsigned* O = sel == 0 ? O0 : (sel == 1 ? O1 : O2);
        int o = l >> 6, pp = (l & 63) * 2;
        int k0 = (pp & 7) * 16 + (pp >> 3);
        int k1 = ((pp + 1) & 7) * 16 + ((pp + 1) >> 3);
        O[l] = pack_bf2(W[o * 128 + k0], W[o * 128 + k1]);
    }
}

// ---------------- CSR build: bucketed 2-phase counting sort ----------------

__global__ __launch_bounds__(256) void bucket_count_kernel(const int* __restrict__ dst,
                                                           int* __restrict__ gbucket,
                                                           int E, int NB) {
    __shared__ int hist[512];
    int t = threadIdx.x;
    for (int b = t; b < NB; b += 256) hist[b] = 0;
    __syncthreads();
    int base = blockIdx.x * 4096;
    #pragma unroll
    for (int j = 0; j < 16; ++j) {
        int e = base + j * 256 + t;
        if (e < E) atomicAdd(&hist[dst[e] >> BSH], 1);
    }
    __syncthreads();
    for (int b = t; b < NB; b += 256) {
        int v = hist[b];
        if (v) atomicAdd(&gbucket[b], v);
    }
}

__global__ void bucket_scan_kernel(const int* __restrict__ gbucket, int* __restrict__ bstart,
                                   int* __restrict__ gcur, int NB, int E) {
    __shared__ int sm[512];
    int t = threadIdx.x;
    int v = (t < NB) ? gbucket[t] : 0;
    sm[t] = v;
    __syncthreads();
    for (int off = 1; off < 512; off <<= 1) {
        int add = (t >= off) ? sm[t - off] : 0;
        __syncthreads();
        sm[t] += add;
        __syncthreads();
    }
    if (t < NB) {
        int ex = sm[t] - v;
        bstart[t] = ex;
        gcur[t] = ex;
    }
    if (t == 0) bstart[NB] = E;
}

__global__ __launch_bounds__(256) void bucket_scatter_kernel(const int* __restrict__ src,
                                                             const int* __restrict__ dst,
                                                             int* __restrict__ gcur,
                                                             uint2* __restrict__ staging,
                                                             int E, int NB) {
    __shared__ int hist[512];
    __shared__ int base[512];
    int t = threadIdx.x;
    for (int b = t; b < NB; b += 256) hist[b] = 0;
    __syncthreads();
    int s[16], d[16], r[16];
    int e0 = blockIdx.x * 4096;
    #pragma unroll
    for (int j = 0; j < 16; ++j) {
        int e = e0 + j * 256 + t;
        if (e < E) {
            s[j] = src[e];
            d[j] = dst[e];
            r[j] = atomicAdd(&hist[d[j] >> BSH], 1);
        } else d[j] = -1;
    }
    __syncthreads();
    for (int b = t; b < NB; b += 256) {
        int v = hist[b];
        base[b] = v ? atomicAdd(&gcur[b], v) : 0;
    }
    __syncthreads();
    #pragma unroll
    for (int j = 0; j < 16; ++j) {
        if (d[j] >= 0) {
            int b = d[j] >> BSH;
            staging[base[b] + r[j]] = make_uint2((unsigned)s[j], (unsigned)d[j]);
        }
    }
}

__global__ __launch_bounds__(256) void csr_build_kernel(const uint2* __restrict__ staging,
                                                        const int* __restrict__ bstart,
                                                        int* __restrict__ rp, int* __restrict__ csr,
                                                        float* __restrict__ degf,
                                                        int N, int E, int NB) {
    __shared__ int hist[256];
    __shared__ int sm[256];
    __shared__ int excl[256];
    __shared__ int cnt[256];
    int t = threadIdx.x;
    int b = blockIdx.x;
    int nbase = b << BSH;
    int s0 = bstart[b], e1 = bstart[b + 1];
    hist[t] = 0;
    __syncthreads();
    for (int i = s0 + t; i < e1; i += 256) {
        uint2 p = staging[i];
        atomicAdd(&hist[p.y & (BNODES - 1)], 1);
    }
    __syncthreads();
    int h = hist[t];
    sm[t] = h;
    __syncthreads();
    for (int off = 1; off < 256; off <<= 1) {
        int add = (t >= off) ? sm[t - off] : 0;
        __syncthreads();
        sm[t] += add;
        __syncthreads();
    }
    excl[t] = sm[t] - h;
    cnt[t] = 0;
    int n = nbase + t;
    if (n < N) {
        rp[n] = s0 + (sm[t] - h);
        degf[n] = (float)h;
    }
    if (b == NB - 1 && t == 0) rp[N] = E;
    __syncthreads();
    for (int i = s0 + t; i < e1; i += 256) {
        uint2 p = staging[i];
        int dl = p.y & (BNODES - 1);
        int pos = s0 + excl[dl] + atomicAdd(&cnt[dl], 1);
        csr[pos] = (int)p.x;
    }
}

// ---------------- h0 in fp8, permuted layout (logical col0 zeroed; deg exact via degf) ----------------

__global__ void build_h0_kernel(const float* __restrict__ feat,
                                unsigned* __restrict__ h8, int N) {
    int id = blockIdx.x * blockDim.x + threadIdx.x;
    if (id >= N * 32) return;
    int n = id >> 5, c = id & 31;
    const float* fr = feat + (size_t)n * NRAW;
    int base = c >> 1, hb = (c & 1) * 4;
    float f[4];
    #pragma unroll
    for (int j = 0; j < 4; ++j) {
        int l = (hb + j) * 16 + base;   // logical col at physical byte 4c+j
        f[j] = (l == 0) ? 0.f : fr[l - 1];
    }
    unsigned w = __builtin_amdgcn_cvt_pk_fp8_f32(f[0], f[1], 0, false);
    w = __builtin_amdgcn_cvt_pk_fp8_f32(f[2], f[3], w, true);
    h8[id] = w;
}

// ---------------- aggregation: fp8 gather, 16 lanes per node, unroll-4 ----------------
// Column-wise independent mean -> permutation-agnostic. h8 [N][16] uint2 rows.

__global__ __launch_bounds__(256) void agg_fp8_kernel(const unsigned* __restrict__ h8,
                                                      unsigned* __restrict__ agg,
                                                      const int* __restrict__ rp,
                                                      const int* __restrict__ csr,
                                                      const float* __restrict__ degf, int N) {
    int t = threadIdx.x;
    int col = t & 15;
    int i = blockIdx.x * 16 + (t >> 4);   // 16 nodes per 256-thread block
    if (i >= N) return;
    int start = rp[i], end = rp[i + 1];
    int deg = end - start;
    const uint2* h2 = (const uint2*)h8;
    if (deg == 0) {
        uint2 v = h2[(size_t)i * 16 + col];
        floatx2 l0 = __builtin_amdgcn_cvt_pk_f32_fp8(v.x, false);
        floatx2 h0 = __builtin_amdgcn_cvt_pk_f32_fp8(v.x, true);
        floatx2 l1 = __builtin_amdgcn_cvt_pk_f32_fp8(v.y, false);
        floatx2 h1 = __builtin_amdgcn_cvt_pk_f32_fp8(v.y, true);
        uint4 r;
        r.x = pack_bf2(l0[0], l0[1]);
        r.y = pack_bf2(h0[0], h0[1]);
        r.z = pack_bf2(l1[0], l1[1]);
        r.w = pack_bf2(h1[0], h1[1]);
        ((uint4*)agg)[(size_t)i * 16 + col] = r;
        return;
    }
    floatx2 a0 = {0.f, 0.f}, a1 = {0.f, 0.f}, a2 = {0.f, 0.f}, a3 = {0.f, 0.f};
    float dsum = 0.f;
    int p = start;
    for (; p + 4 <= end; p += 4) {
        int i0 = csr[p];
        int i1 = csr[p + 1];
        int i2 = csr[p + 2];
        int i3 = csr[p + 3];
        uint2 v0 = h2[(size_t)i0 * 16 + col];
        uint2 v1 = h2[(size_t)i1 * 16 + col];
        uint2 v2 = h2[(size_t)i2 * 16 + col];
        uint2 v3 = h2[(size_t)i3 * 16 + col];
        if (degf && col == 0) dsum += degf[i0] + degf[i1] + degf[i2] + degf[i3];
        a0 += __builtin_amdgcn_cvt_pk_f32_fp8(v0.x, false);
        a1 += __builtin_amdgcn_cvt_pk_f32_fp8(v0.x, true);
        a2 += __builtin_amdgcn_cvt_pk_f32_fp8(v0.y, false);
        a3 += __builtin_amdgcn_cvt_pk_f32_fp8(v0.y, true);
        a0 += __builtin_amdgcn_cvt_pk_f32_fp8(v1.x, false);
        a1 += __builtin_amdgcn_cvt_pk_f32_fp8(v1.x, true);
        a2 += __builtin_amdgcn_cvt_pk_f32_fp8(v1.y, false);
        a3 += __builtin_amdgcn_cvt_pk_f32_fp8(v1.y, true);
        a0 += __builtin_amdgcn_cvt_pk_f32_fp8(v2.x, false);
        a1 += __builtin_amdgcn_cvt_pk_f32_fp8(v2.x, true);
        a2 += __builtin_amdgcn_cvt_pk_f32_fp8(v2.y, false);
        a3 += __builtin_amdgcn_cvt_pk_f32_fp8(v2.y, true);
        a0 += __builtin_amdgcn_cvt_pk_f32_fp8(v3.x, false);
        a1 += __builtin_amdgcn_cvt_pk_f32_fp8(v3.x, true);
        a2 += __builtin_amdgcn_cvt_pk_f32_fp8(v3.y, false);
        a3 += __builtin_amdgcn_cvt_pk_f32_fp8(v3.y, true);
    }
    for (; p < end; ++p) {
        int i0 = csr[p];
        uint2 v0 = h2[(size_t)i0 * 16 + col];
        if (degf && col == 0) dsum += degf[i0];
        a0 += __builtin_amdgcn_cvt_pk_f32_fp8(v0.x, false);
        a1 += __builtin_amdgcn_cvt_pk_f32_fp8(v0.x, true);
        a2 += __builtin_amdgcn_cvt_pk_f32_fp8(v0.y, false);
        a3 += __builtin_amdgcn_cvt_pk_f32_fp8(v0.y, true);
    }
    if (degf && col == 0) a0[0] = dsum;   // exact neighbor-deg sum -> logical col 0 (phys byte 0)
    float inv = 1.f / (float)deg;
    uint4 r;
    r.x = pack_bf2(a0[0] * inv, a0[1] * inv);
    r.y = pack_bf2(a1[0] * inv, a1[1] * inv);
    r.z = pack_bf2(a2[0] * inv, a2[1] * inv);
    r.w = pack_bf2(a3[0] * inv, a3[1] * inv);
    ((uint4*)agg)[(size_t)i * 16 + col] = r;
}

// ---------------- GEMM: relu(A @ W^T + b) via MFMA bf16; coalesced permuted stores ----------------
// A [N,128] bf16 (k physical order), Wb [128][64 u32] bf16 k-permuted. Epilogue: lane (m,q)
// holds C[rows q*4+r][logical cols ot*16+m] -> packs its 8 ot-values into contiguous bytes at
// physical positions m*8+0..7 -> one uint2 (fp8) / uint4 (bf16) store per row. Full-line writes.

__global__ __launch_bounds__(256) void mfma_gemm_kernel(const unsigned* __restrict__ A,
                                                        unsigned* __restrict__ out8,
                                                        unsigned* __restrict__ outb,
                                                        const unsigned* __restrict__ Wb,
                                                        const float* __restrict__ bias, int N) {
    __shared__ unsigned Al[64 * APAD];
    int t = threadIdx.x;
    int n0 = blockIdx.x * 64;
    #pragma unroll
    for (int c = 0; c < 4; ++c) {
        int f = c * 256 + t;
        int row = f >> 4, c4 = f & 15;
        int n = n0 + row;
        uint4 v = make_uint4(0u, 0u, 0u, 0u);
        if (n < N) v = ((const uint4*)A)[(size_t)n * 16 + c4];
        *(uint4*)&Al[row * APAD + c4 * 4] = v;
    }
    __syncthreads();

    int wv = t >> 6, lane = t & 63;
    int m = lane & 15, q = lane >> 4;
    floatx4 acc[8];
    #pragma unroll
    for (int ot = 0; ot < 8; ++ot) acc[ot] = (floatx4)(0.f);

    #pragma unroll
    for (int kt = 0; kt < 4; ++kt) {
        short8 af = *(const short8*)&Al[(wv * 16 + m) * APAD + kt * 16 + q * 4];
        short8 bf[8];
        #pragma unroll
        for (int ot = 0; ot < 8; ++ot)
            bf[ot] = *(const short8*)&Wb[(ot * 16 + m) * 64 + kt * 16 + q * 4];
        #pragma unroll
        for (int ot = 0; ot < 8; ++ot)
            acc[ot] = __builtin_amdgcn_mfma_f32_16x16x32_bf16(af, bf[ot], acc[ot], 0, 0, 0);
    }

    float bv[8];
    #pragma unroll
    for (int ot = 0; ot < 8; ++ot) bv[ot] = bias[ot * 16 + m];

    #pragma unroll
    for (int r = 0; r < 4; ++r) {
        int n = n0 + wv * 16 + q * 4 + r;
        if (n < N) {
            float vv[8];
            #pragma unroll
            for (int ot = 0; ot < 8; ++ot) vv[ot] = fmaxf(acc[ot][r] + bv[ot], 0.f);
            if (out8) {
                unsigned w0 = __builtin_amdgcn_cvt_pk_fp8_f32(vv[0], vv[1], 0, false);
                w0 = __builtin_amdgcn_cvt_pk_fp8_f32(vv[2], vv[3], w0, true);
                unsigned w1 = __builtin_amdgcn_cvt_pk_fp8_f32(vv[4], vv[5], 0, false);
                w1 = __builtin_amdgcn_cvt_pk_fp8_f32(vv[6], vv[7], w1, true);
                ((uint2*)out8)[(size_t)n * 16 + m] = make_uint2(w0, w1);
            }
            if (outb) {
                uint4 w;
                w.x = pack_bf2(vv[0], vv[1]);
                w.y = pack_bf2(vv[2], vv[3]);
                w.z = pack_bf2(vv[4], vv[5]);
                w.w = pack_bf2(vv[6], vv[7]);
                ((uint4*)outb)[(size_t)n * 16 + m] = w;
            }
        }
    }
}

// ---------------- graph mean-pool + counts: 64-node blocks, 4-way node striping ----------------

__global__ __launch_bounds__(256) void pool_kernel(const unsigned* __restrict__ h,
                                                   const int* __restrict__ gid,
                                                   float* __restrict__ hg,
                                                   float* __restrict__ counts, int N) {
    int c = threadIdx.x & 63;
    int q = threadIdx.x >> 6;
    int n0 = blockIdx.x * 64;
    int nend = min(n0 + 64, N);
    float ax = 0.f, ay = 0.f, cnt = 0.f;
    int cur = -1;
    for (int n = n0 + q; n < nend; n += 4) {
        int g = gid[n];
        if (g != cur) {
            if (cur >= 0) {
                atomicAdd(&hg[cur * HID + 2 * c], ax);
                atomicAdd(&hg[cur * HID + 2 * c + 1], ay);
                if (c == 0) atomicAdd(&counts[cur], cnt);
            }
            ax = ay = cnt = 0.f;
            cur = g;
        }
        unsigned v = h[(size_t)n * 64 + c];
        ax += bf_lo(v); ay += bf_hi(v);
        cnt += 1.f;
    }
    if (cur >= 0) {
        atomicAdd(&hg[cur * HID + 2 * c], ax);
        atomicAdd(&hg[cur * HID + 2 * c + 1], ay);
        if (c == 0) atomicAdd(&counts[cur], cnt);
    }
}

// ---------------- fused classifier head (fp32), one block per graph ----------------
// hg is in permuted physical order -> first matmul uses Wc1p (k-permuted); y is logical after.

__global__ __launch_bounds__(128) void cls_fused_kernel(const float* __restrict__ hg,
                                                        const float* __restrict__ counts,
                                                        const float* __restrict__ Wc1p,
                                                        const float* __restrict__ Wc1,
                                                        const float* __restrict__ bc1,
                                                        const float* __restrict__ Wc2,
                                                        const float* __restrict__ bc2,
                                                        float* __restrict__ out, int G) {
    __shared__ float x[128];
    __shared__ float y[128];
    __shared__ float red[128];
    int g = blockIdx.x, t = threadIdx.x;
    float inv = 1.f / fmaxf(counts[g], 1.f);
    x[t] = hg[g * HID + t] * inv;
    __syncthreads();
    const float4* wp4 = (const float4*)(Wc1p + t * HID);
    float s = 0.f;
    #pragma unroll
    for (int k4 = 0; k4 < 32; ++k4) {
        float4 w = wp4[k4];
        s += x[k4 * 4] * w.x + x[k4 * 4 + 1] * w.y + x[k4 * 4 + 2] * w.z + x[k4 * 4 + 3] * w.w;
    }
    y[t] = s + bc1[t];
    __syncthreads();
    const float4* w4 = (const float4*)(Wc1 + t * HID);
    float s2 = 0.f;
    #pragma unroll
    for (int k4 = 0; k4 < 32; ++k4) {
        float4 w = w4[k4];
        s2 += y[k4 * 4] * w.x + y[k4 * 4 + 1] * w.y + y[k4 * 4 + 2] * w.z + y[k4 * 4 + 3] * w.w;
    }
    red[t] = (s2 + bc1[t]) * Wc2[t];
    __syncthreads();
    if (t < 64) {
        float r = red[t] + red[t + 64];
        #pragma unroll
        for (int off = 32; off > 0; off >>= 1) r += __shfl_down(r, off);
        if (t == 0) out[g] = r + bc2[0];
    }
}

// ---------------- launch ----------------

extern "C" void kernel_launch(void* const* d_in, const int* in_sizes, int n_in,
                              void* d_out, int out_size, void* d_ws, size_t ws_size,
                              hipStream_t stream) {
    const float* feat = (const float*)d_in[0];
    const int* src    = (const int*)d_in[1];
    const int* dst    = (const int*)d_in[2];
    const int* gid    = (const int*)d_in[3];
    const float* W0  = (const float*)d_in[5];
    const float* b0  = (const float*)d_in[6];
    const float* W1  = (const float*)d_in[7];
    const float* b1  = (const float*)d_in[8];
    const float* W2  = (const float*)d_in[9];
    const float* b2  = (const float*)d_in[10];
    const float* Wc1 = (const float*)d_in[11];
    const float* bc1 = (const float*)d_in[12];
    const float* Wc2 = (const float*)d_in[13];
    const float* bc2 = (const float*)d_in[14];

    const int N = in_sizes[3];
    const int E = in_sizes[1];
    const int G = out_size;
    const int NB = (N + BNODES - 1) >> BSH;

    char* ws = (char*)d_ws;
    size_t off = 0;
    auto alloc = [&](size_t bytes) { void* p = ws + off; off += (bytes + 255) & ~size_t(255); return p; };
    unsigned* h8     = (unsigned*)alloc((size_t)N * 32 * 4);   // fp8 h, permuted cols
    unsigned* hB     = (unsigned*)alloc((size_t)N * 64 * 4);   // bf16 h3, permuted cols
    unsigned* aggbuf = (unsigned*)alloc((size_t)N * 64 * 4);   // bf16 GEMM input, permuted cols
    float* degf      = (float*)alloc((size_t)N * 4);
    uint2* staging   = (uint2*)alloc((size_t)E * 8);
    int* csr         = (int*)alloc((size_t)E * 4);
    int* rp          = (int*)alloc((size_t)(N + 1) * 4);
    int* gbucket     = (int*)alloc(512 * 4);
    int* bstart      = (int*)alloc(513 * 4);
    int* gcur        = (int*)alloc(512 * 4);
    unsigned* Wb0    = (unsigned*)alloc(8192 * 4);
    unsigned* Wb1    = (unsigned*)alloc(8192 * 4);
    unsigned* Wb2    = (unsigned*)alloc(8192 * 4);
    float* Wc1p      = (float*)alloc(16384 * 4);
    float* hg        = (float*)alloc((size_t)G * HID * 4);
    float* counts    = (float*)alloc((size_t)G * 4);

    init_kernel<<<96, 256, 0, stream>>>(W0, W1, W2, Wc1, Wb0, Wb1, Wb2, Wc1p,
                                        gbucket, hg, counts, G);

    int gE = (E + 4095) / 4096;
    bucket_count_kernel<<<gE, 256, 0, stream>>>(dst, gbucket, E, NB);
    bucket_scan_kernel<<<1, 512, 0, stream>>>(gbucket, bstart, gcur, NB, E);
    bucket_scatter_kernel<<<gE, 256, 0, stream>>>(src, dst, gcur, staging, E, NB);
    csr_build_kernel<<<NB, 256, 0, stream>>>(staging, bstart, rp, csr, degf, N, E, NB);

    build_h0_kernel<<<(N * 32 + 255) / 256, 256, 0, stream>>>(feat, h8, N);

    int agg_grid = (N + 15) / 16;
    int gemm_grid = (N + 63) / 64;

    agg_fp8_kernel<<<agg_grid, 256, 0, stream>>>(h8, aggbuf, rp, csr, degf, N);
    mfma_gemm_kernel<<<gemm_grid, 256, 0, stream>>>(aggbuf, h8, nullptr, Wb0, b0, N);

    agg_fp8_kernel<<<agg_grid, 256, 0, stream>>>(h8, aggbuf, rp, csr, nullptr, N);
    mfma_gemm_kernel<<<gemm_grid, 256, 0, stream>>>(aggbuf, h8, nullptr, Wb1, b1, N);

    agg_fp8_kernel<<<agg_grid, 256, 0, stream>>>(h8, aggbuf, rp, csr, nullptr, N);
    mfma_gemm_kernel<<<gemm_grid, 256, 0, stream>>>(aggbuf, nullptr, hB, Wb2, b2, N);

    pool_kernel<<<(N + 63) / 64, 256, 0, stream>>>(hB, gid, hg, counts, N);

    cls_fused_kernel<<<G, 128, 0, stream>>>(hg, counts, Wc1p, Wc1, bc1, Wc2, bc2,
                                            (float*)d_out, G);
}